// Round 3
// baseline (560.501 us; speedup 1.0000x reference)
//
#include <hip/hip_runtime.h>
#include <hip/hip_bf16.h>

#define BGR   128
#define NPER  1024
#define NK    7
#define NNODES (BGR*NPER)

typedef __attribute__((ext_vector_type(8))) short short8;
typedef __attribute__((ext_vector_type(8))) unsigned short ushort8;
typedef __attribute__((ext_vector_type(4))) float floatx4;

static __device__ __forceinline__ float bf2f(unsigned short u) {
    unsigned int x = ((unsigned int)u) << 16;
    return __builtin_bit_cast(float, x);
}
static __device__ __forceinline__ unsigned short f2bf(float f) {
    unsigned int x = __builtin_bit_cast(unsigned int, f);
    unsigned int lsb = (x >> 16) & 1u;
    x += 0x7fffu + lsb;
    return (unsigned short)(x >> 16);
}

// ---------------- 0: repack pos into float4 ----------------
__global__ __launch_bounds__(256) void repack_pos_kernel(const float* __restrict__ pos,
                                                         floatx4* __restrict__ p4) {
    int i = blockIdx.x * blockDim.x + threadIdx.x;
    if (i < NNODES) {
        floatx4 v;
        v.x = pos[(size_t)i*3+0]; v.y = pos[(size_t)i*3+1]; v.z = pos[(size_t)i*3+2]; v.w = 0.f;
        p4[i] = v;
    }
}

// ---------------- 1: kNN — pass1 distances-only (branchless min/max chain),
//                     pass2 recompute + index collect (bit-identical fmaf) ----------------
__global__ __launch_bounds__(256) void knn_kernel(const floatx4* __restrict__ p4,
                                                  int* __restrict__ idx) {
    __shared__ floatx4 sp[NPER];
    int g = blockIdx.x >> 2;
    int i_local = ((blockIdx.x & 3) << 8) + threadIdx.x;
    int base = g * NPER;
    const floatx4* pg = p4 + base;
    for (int j = threadIdx.x; j < NPER; j += 256) sp[j] = pg[j];
    __syncthreads();
    floatx4 me = sp[i_local];

    // pass 1: 7 smallest distance VALUES, sorted b0<=..<=b6 (no indices)
    float b0=3e38f,b1=3e38f,b2=3e38f,b3=3e38f,b4=3e38f,b5=3e38f,b6=3e38f;
    for (int j0 = 0; j0 < NPER; j0 += 8) {
        #pragma unroll
        for (int u = 0; u < 8; ++u) {
            floatx4 q = sp[j0 + u];
            float dx = me.x-q.x, dy = me.y-q.y, dz = me.z-q.z;
            float d = fmaf(dx,dx, fmaf(dy,dy, dz*dz));
            d = (j0 + u == i_local) ? 3e38f : d;
            if (d < b6) {
                float t = d;
                #define INS(bb) { float mn = fminf(bb,t); t = fmaxf(bb,t); bb = mn; }
                INS(b0) INS(b1) INS(b2) INS(b3) INS(b4) INS(b5)
                #undef INS
                b6 = fminf(b6, t);
            }
        }
    }

    // pass 2: collect the indices with d <= b6 (exactly the top-7; order irrelevant)
    int i0=0,i1=0,i2=0,i3=0,i4=0,i5=0,i6=0;
    for (int j0 = 0; j0 < NPER; j0 += 8) {
        #pragma unroll
        for (int u = 0; u < 8; ++u) {
            floatx4 q = sp[j0 + u];
            float dx = me.x-q.x, dy = me.y-q.y, dz = me.z-q.z;
            float d = fmaf(dx,dx, fmaf(dy,dy, dz*dz));
            if (d <= b6 && (j0 + u != i_local)) {
                i6=i5; i5=i4; i4=i3; i3=i2; i2=i1; i1=i0; i0=j0+u;
            }
        }
    }
    int* op = idx + (size_t)(base + i_local) * NK;
    op[0]=base+i0; op[1]=base+i1; op[2]=base+i2; op[3]=base+i3;
    op[4]=base+i4; op[5]=base+i5; op[6]=base+i6;
}

// ---------------- 2: feat1 — x(16) -> kf/qf/vf/sk (64), W in registers ----------------
__global__ __launch_bounds__(256) void feat1_kernel(
    const float* __restrict__ x,
    const float* __restrict__ wk, const float* __restrict__ bk,
    const float* __restrict__ wq, const float* __restrict__ bq,
    const float* __restrict__ wv, const float* __restrict__ bv,
    const float* __restrict__ wsm, const float* __restrict__ bs,
    unsigned short* __restrict__ kf, unsigned short* __restrict__ qf,
    unsigned short* __restrict__ vf, unsigned short* __restrict__ sk) {
    int c = threadIdx.x & 63;
    float Wk[16], Wq[16], Wv[16], Ws[16];
    #pragma unroll
    for (int k = 0; k < 16; ++k) {
        Wk[k] = wk[k*64+c]; Wq[k] = wq[k*64+c]; Wv[k] = wv[k*64+c]; Ws[k] = wsm[k*64+c];
    }
    float Bk = bk[c], Bq = bq[c], Bv = bv[c], Bs = bs[c];
    int wave = blockIdx.x * (blockDim.x >> 6) + (threadIdx.x >> 6);
    int nw   = gridDim.x * (blockDim.x >> 6);
    for (int n = wave; n < NNODES; n += nw) {
        const float* xr = x + (size_t)n * 16;
        float ak = Bk, aq = Bq, av = Bv, as = Bs;
        #pragma unroll
        for (int k = 0; k < 16; ++k) {
            float xv = xr[k];
            ak += xv * Wk[k]; aq += xv * Wq[k]; av += xv * Wv[k]; as += xv * Ws[k];
        }
        size_t o = (size_t)n * 64 + c;
        kf[o] = f2bf(ak); qf[o] = f2bf(aq); vf[o] = f2bf(av); sk[o] = f2bf(as);
    }
}

// ---------------- 3: gated conv — XCD-swizzled: each XCD owns 16 whole graphs ----------------
template<int C>
__global__ __launch_bounds__(256) void conv_kernel(
    const unsigned short* __restrict__ kf, const unsigned short* __restrict__ qf,
    const unsigned short* __restrict__ vf, const unsigned short* __restrict__ sk,
    const int* __restrict__ idx, unsigned short* __restrict__ h) {
    const int NPB = 256 / C;
    int c   = threadIdx.x & (C - 1);
    int sub = threadIdx.x / C;
    // blockIdx round-robins over 8 XCDs; map so graph's 32 blocks share an XCD
    int b     = blockIdx.x;            // 4096 total = 128 graphs x 32
    int xcd   = b & 7;
    int chunk = b >> 3;                // 0..511
    int graph = xcd * 16 + (chunk >> 5);
    int nblk  = chunk & 31;
    int n0 = graph * NPER + nblk * 32;
    for (int i = sub; i < 32; i += NPB) {
        int n = n0 + i;
        const int* nb = idx + (size_t)n * NK;
        size_t o = (size_t)n * C + c;
        float kv  = bf2f(kf[o]);
        float acc = bf2f(sk[o]);
        #pragma unroll
        for (int k = 0; k < NK; ++k) {
            int j = nb[k];
            float qv = bf2f(qf[(size_t)j * C + c]);
            float vv = bf2f(vf[(size_t)j * C + c]);
            float t = kv + qv;
            float s = 1.f / (1.f + __expf(-t));
            acc += s * vv;
        }
        h[o] = f2bf(acc);
    }
}

// ---------------- 4: BN stats (deterministic two-stage) ----------------
template<int C>
__global__ __launch_bounds__(256) void bn_stats_kernel(const unsigned short* __restrict__ h,
                                                       float* __restrict__ part) {
    const int LPB = 256 / C;
    int c = threadIdx.x & (C - 1);
    int sub = threadIdx.x / C;
    const int nodesPer = NNODES / 256;
    int n0 = blockIdx.x * nodesPer;
    float s = 0.f, s2 = 0.f;
    for (int i = sub; i < nodesPer; i += LPB) {
        float v = bf2f(h[(size_t)(n0 + i) * C + c]);
        s += v; s2 += v * v;
    }
    __shared__ float ls[256], ls2[256];
    ls[threadIdx.x] = s; ls2[threadIdx.x] = s2;
    __syncthreads();
    if (threadIdx.x < C) {
        #pragma unroll
        for (int l = 1; l < LPB; ++l) { s += ls[threadIdx.x + l*C]; s2 += ls2[threadIdx.x + l*C]; }
        part[(size_t)blockIdx.x * 2 * C + c]     = s;
        part[(size_t)blockIdx.x * 2 * C + C + c] = s2;
    }
}

__global__ void bn_finalize_kernel(const float* __restrict__ part,
                                   const float* __restrict__ gamma, const float* __restrict__ beta,
                                   float* __restrict__ ss, int C) {
    int c = threadIdx.x;
    if (c >= C) return;
    float s = 0.f, s2 = 0.f;
    for (int b = 0; b < 256; ++b) { s += part[(size_t)b*2*C + c]; s2 += part[(size_t)b*2*C + C + c]; }
    float m   = s / (float)NNODES;
    float var = s2 / (float)NNODES - m * m;
    float inv = rsqrtf(var + 1e-5f);
    float sc  = gamma[c] * inv;
    ss[c]     = sc;
    ss[C + c] = beta[c] - m * sc;
}

// ---------------- 6: bf16 MFMA B-fragments for the 4 layer-2 weights ----------------
__global__ __launch_bounds__(64) void wfrag_kernel(
    const float* __restrict__ w0, const float* __restrict__ w1,
    const float* __restrict__ w2, const float* __restrict__ w3,
    unsigned short* __restrict__ frag) {
    int m  = blockIdx.x >> 4;
    int kt = (blockIdx.x >> 3) & 1;
    int ct = blockIdx.x & 7;
    const float* w = (m == 0) ? w0 : (m == 1) ? w1 : (m == 2) ? w2 : w3;
    int l = threadIdx.x;
    int col = ct * 16 + (l & 15);
    int kbase = kt * 32 + (l >> 4) * 8;
    unsigned short* out = frag + ((size_t)blockIdx.x * 64 + l) * 8;
    #pragma unroll
    for (int e = 0; e < 8; ++e) out[e] = f2bf(w[(size_t)(kbase + e) * 128 + col]);
}

// ---------------- 7: feat2 — fused BN1+ReLU on load, all 8 col-tiles per block ----------------
__global__ __launch_bounds__(256) void feat2_kernel(
    const unsigned short* __restrict__ h1n, const unsigned short* __restrict__ frag,
    const float* __restrict__ ss1,
    const float* __restrict__ b0, const float* __restrict__ b1,
    const float* __restrict__ b2, const float* __restrict__ b3,
    unsigned short* __restrict__ o0, unsigned short* __restrict__ o1,
    unsigned short* __restrict__ o2, unsigned short* __restrict__ o3) {
    int nt = blockIdx.x;
    int m  = threadIdx.x >> 6;
    int l  = threadIdx.x & 63;
    const float* bm        = (m == 0) ? b0 : (m == 1) ? b1 : (m == 2) ? b2 : b3;
    unsigned short* om     = (m == 0) ? o0 : (m == 1) ? o1 : (m == 2) ? o2 : o3;
    int lr = l & 15;
    int gq = l >> 4;
    int n  = nt * 16 + lr;
    const unsigned short* ar = h1n + (size_t)n * 64 + gq * 8;
    short8 a0r = *(const short8*)ar;
    short8 a1r = *(const short8*)(ar + 32);
    short8 a0, a1;
    #pragma unroll
    for (int e = 0; e < 8; ++e) {
        int c0 = gq * 8 + e;
        float f0 = bf2f((unsigned short)a0r[e]) * ss1[c0] + ss1[64 + c0];
        a0[e] = (short)f2bf(fmaxf(f0, 0.f));
        int c1 = 32 + gq * 8 + e;
        float f1 = bf2f((unsigned short)a1r[e]) * ss1[c1] + ss1[64 + c1];
        a1[e] = (short)f2bf(fmaxf(f1, 0.f));
    }
    #pragma unroll
    for (int ct = 0; ct < 8; ++ct) {
        size_t fb0 = ((size_t)(m * 16 + ct)     * 64 + l) * 8;
        size_t fb1 = ((size_t)(m * 16 + 8 + ct) * 64 + l) * 8;
        short8 w0 = *(const short8*)(frag + fb0);
        short8 w1 = *(const short8*)(frag + fb1);
        float bv = bm[ct * 16 + lr];
        floatx4 acc = {bv, bv, bv, bv};
        acc = __builtin_amdgcn_mfma_f32_16x16x32_bf16(a0, w0, acc, 0, 0, 0);
        acc = __builtin_amdgcn_mfma_f32_16x16x32_bf16(a1, w1, acc, 0, 0, 0);
        int ocol = ct * 16 + lr;
        #pragma unroll
        for (int r = 0; r < 4; ++r) {
            int orow = nt * 16 + gq * 4 + r;
            om[(size_t)orow * 128 + ocol] = f2bf(acc[r]);
        }
    }
}

// ---------------- 8: mean-pool with fused BN2+ReLU, two-stage ----------------
__global__ __launch_bounds__(256) void pool_partial_kernel(const unsigned short* __restrict__ h2,
                                                           const float* __restrict__ ss2,
                                                           float* __restrict__ part) {
    int g = blockIdx.x >> 2;
    int q = blockIdx.x & 3;
    int c = threadIdx.x & 127;
    int isub = threadIdx.x >> 7;  // 0..1
    float sc = ss2[c], sh = ss2[128 + c];
    float acc = 0.f;
    const unsigned short* hp = h2 + ((size_t)g * NPER + q * 256) * 128;
    for (int i = isub; i < 256; i += 2)
        acc += fmaxf(bf2f(hp[(size_t)i * 128 + c]) * sc + sh, 0.f);
    __shared__ float red[256];
    red[threadIdx.x] = acc;
    __syncthreads();
    if (threadIdx.x < 128)
        part[(size_t)blockIdx.x * 128 + c] = acc + red[threadIdx.x + 128];
}

__global__ void pool_final_kernel(const float* __restrict__ part, float* __restrict__ out) {
    int g = blockIdx.x, c = threadIdx.x;
    float s = part[(size_t)(g*4+0)*128+c] + part[(size_t)(g*4+1)*128+c]
            + part[(size_t)(g*4+2)*128+c] + part[(size_t)(g*4+3)*128+c];
    out[(size_t)g * 128 + c] = s * (1.f / 1024.f);
}

extern "C" void kernel_launch(void* const* d_in, const int* in_sizes, int n_in,
                              void* d_out, int out_size, void* d_ws, size_t ws_size,
                              hipStream_t stream) {
    const float* x   = (const float*)d_in[0];
    const float* pos = (const float*)d_in[1];
    const float* wk1 = (const float*)d_in[3];
    const float* bk1 = (const float*)d_in[4];
    const float* wq1 = (const float*)d_in[5];
    const float* bq1 = (const float*)d_in[6];
    const float* wv1 = (const float*)d_in[7];
    const float* bv1 = (const float*)d_in[8];
    const float* ws1 = (const float*)d_in[9];
    const float* bs1 = (const float*)d_in[10];
    const float* g1  = (const float*)d_in[11];
    const float* be1 = (const float*)d_in[12];
    const float* wk2 = (const float*)d_in[13];
    const float* bk2 = (const float*)d_in[14];
    const float* wq2 = (const float*)d_in[15];
    const float* bq2 = (const float*)d_in[16];
    const float* wv2 = (const float*)d_in[17];
    const float* bv2 = (const float*)d_in[18];
    const float* ws2 = (const float*)d_in[19];
    const float* bs2 = (const float*)d_in[20];
    const float* g2  = (const float*)d_in[21];
    const float* be2 = (const float*)d_in[22];
    float* out = (float*)d_out;

    const size_t SZ_F1 = (size_t)NNODES * 64 * 2;   // 16 MiB
    const size_t SZ_F2 = (size_t)NNODES * 128 * 2;  // 32 MiB

    char* ws = (char*)d_ws;
    size_t off = 0;
    auto alloc = [&](size_t b) { size_t o = off; off += (b + 255) & ~(size_t)255; return o; };

    int* idx              = (int*)(ws + alloc((size_t)NNODES * NK * 4));
    size_t o_region       = alloc(4 * SZ_F2);       // kqvs2 region; kqvs1 aliased in front
    unsigned short* kf1   = (unsigned short*)(ws + o_region);
    unsigned short* qf1   = (unsigned short*)(ws + o_region + SZ_F1);
    unsigned short* vf1   = (unsigned short*)(ws + o_region + 2 * SZ_F1);
    unsigned short* sk1   = (unsigned short*)(ws + o_region + 3 * SZ_F1);
    unsigned short* kf2   = (unsigned short*)(ws + o_region);
    unsigned short* qf2   = (unsigned short*)(ws + o_region + SZ_F2);
    unsigned short* vf2   = (unsigned short*)(ws + o_region + 2 * SZ_F2);
    unsigned short* sk2   = (unsigned short*)(ws + o_region + 3 * SZ_F2);
    unsigned short* h1    = (unsigned short*)(ws + alloc(SZ_F1));
    unsigned short* h2    = (unsigned short*)(ws + alloc(SZ_F2));
    unsigned short* frag  = (unsigned short*)(ws + alloc(64 * 64 * 8 * 2));
    float* part           = (float*)(ws + alloc(512 * 128 * 4));
    float* ss1            = (float*)(ws + alloc(2 * 64 * 4));
    float* ss2            = (float*)(ws + alloc(2 * 128 * 4));
    floatx4* p4           = (floatx4*)(ws + alloc((size_t)NNODES * 16));
    (void)ws_size; (void)in_sizes; (void)n_in; (void)out_size;

    repack_pos_kernel<<<NNODES / 256, 256, 0, stream>>>(pos, p4);
    knn_kernel<<<BGR * 4, 256, 0, stream>>>(p4, idx);
    feat1_kernel<<<1024, 256, 0, stream>>>(x, wk1, bk1, wq1, bq1, wv1, bv1, ws1, bs1,
                                           kf1, qf1, vf1, sk1);
    conv_kernel<64><<<NNODES / 32, 256, 0, stream>>>(kf1, qf1, vf1, sk1, idx, h1);
    bn_stats_kernel<64><<<256, 256, 0, stream>>>(h1, part);
    bn_finalize_kernel<<<1, 64, 0, stream>>>(part, g1, be1, ss1, 64);
    wfrag_kernel<<<64, 64, 0, stream>>>(wk2, wq2, wv2, ws2, frag);
    feat2_kernel<<<NNODES / 16, 256, 0, stream>>>(h1, frag, ss1, bk2, bq2, bv2, bs2,
                                                  kf2, qf2, vf2, sk2);
    conv_kernel<128><<<NNODES / 32, 256, 0, stream>>>(kf2, qf2, vf2, sk2, idx, h2);
    bn_stats_kernel<128><<<256, 256, 0, stream>>>(h2, part);
    bn_finalize_kernel<<<1, 128, 0, stream>>>(part, g2, be2, ss2, 128);
    pool_partial_kernel<<<BGR * 4, 256, 0, stream>>>(h2, ss2, part);
    pool_final_kernel<<<BGR, 128, 0, stream>>>(part, out);
}

// Round 4
// 493.445 us; speedup vs baseline: 1.1359x; 1.1359x over previous
//
#include <hip/hip_runtime.h>
#include <hip/hip_bf16.h>

#define BGR   128
#define NPER  1024
#define NK    7
#define NNODES (BGR*NPER)

typedef __attribute__((ext_vector_type(8))) short short8;
typedef __attribute__((ext_vector_type(8))) unsigned short ushort8;
typedef __attribute__((ext_vector_type(4))) float floatx4;

static __device__ __forceinline__ float bf2f(unsigned short u) {
    unsigned int x = ((unsigned int)u) << 16;
    return __builtin_bit_cast(float, x);
}
static __device__ __forceinline__ unsigned short f2bf(float f) {
    unsigned int x = __builtin_bit_cast(unsigned int, f);
    unsigned int lsb = (x >> 16) & 1u;
    x += 0x7fffu + lsb;
    return (unsigned short)(x >> 16);
}

// ---------------- 1: kNN — branchless two-pass, SoA LDS, direct pos staging ----------------
// pass1: 7 smallest distances via unconditional sorted min/max chain (no branches).
// pass2: recompute d (bit-identical fmaf) + branchless cndmask shift-register index collect.
__global__ __launch_bounds__(256) void knn_kernel(const float* __restrict__ pos,
                                                  int* __restrict__ idx) {
    __shared__ __align__(16) float xs[NPER];
    __shared__ __align__(16) float ys[NPER];
    __shared__ __align__(16) float zs[NPER];
    int g = blockIdx.x >> 2;
    int i_local = ((blockIdx.x & 3) << 8) + threadIdx.x;
    int base = g * NPER;
    const float* pg = pos + (size_t)base * 3;
    for (int t = threadIdx.x; t < NPER * 3; t += 256) {
        float v = pg[t];
        int j = t / 3, comp = t - j * 3;
        if (comp == 0) xs[j] = v; else if (comp == 1) ys[j] = v; else zs[j] = v;
    }
    __syncthreads();
    float mex = xs[i_local], mey = ys[i_local], mez = zs[i_local];

    // pass 1: values only, fully branchless
    float b0=3e38f,b1=3e38f,b2=3e38f,b3=3e38f,b4=3e38f,b5=3e38f,b6=3e38f;
    for (int j0 = 0; j0 < NPER; j0 += 8) {
        floatx4 xa = *(const floatx4*)&xs[j0], xb = *(const floatx4*)&xs[j0+4];
        floatx4 ya = *(const floatx4*)&ys[j0], yb = *(const floatx4*)&ys[j0+4];
        floatx4 za = *(const floatx4*)&zs[j0], zb = *(const floatx4*)&zs[j0+4];
        #pragma unroll
        for (int u = 0; u < 8; ++u) {
            float qx = (u < 4) ? xa[u] : xb[u-4];
            float qy = (u < 4) ? ya[u] : yb[u-4];
            float qz = (u < 4) ? za[u] : zb[u-4];
            float dx = mex-qx, dy = mey-qy, dz = mez-qz;
            float d = fmaf(dx,dx, fmaf(dy,dy, dz*dz));
            d = (j0 + u == i_local) ? 3e38f : d;
            float t = d;
            #define INS(bb) { float mn = fminf(bb,t); t = fmaxf(bb,t); bb = mn; }
            INS(b0) INS(b1) INS(b2) INS(b3) INS(b4) INS(b5)
            #undef INS
            b6 = fminf(b6, t);
        }
    }

    // pass 2: branchless index collection (d <= b6 selects exactly the top-7)
    int i0=0,i1=0,i2=0,i3=0,i4=0,i5=0,i6=0;
    for (int j0 = 0; j0 < NPER; j0 += 8) {
        floatx4 xa = *(const floatx4*)&xs[j0], xb = *(const floatx4*)&xs[j0+4];
        floatx4 ya = *(const floatx4*)&ys[j0], yb = *(const floatx4*)&ys[j0+4];
        floatx4 za = *(const floatx4*)&zs[j0], zb = *(const floatx4*)&zs[j0+4];
        #pragma unroll
        for (int u = 0; u < 8; ++u) {
            float qx = (u < 4) ? xa[u] : xb[u-4];
            float qy = (u < 4) ? ya[u] : yb[u-4];
            float qz = (u < 4) ? za[u] : zb[u-4];
            float dx = mex-qx, dy = mey-qy, dz = mez-qz;
            float d = fmaf(dx,dx, fmaf(dy,dy, dz*dz));
            bool take = (d <= b6) && (j0 + u != i_local);
            i6 = take ? i5 : i6;
            i5 = take ? i4 : i5;
            i4 = take ? i3 : i4;
            i3 = take ? i2 : i3;
            i2 = take ? i1 : i2;
            i1 = take ? i0 : i1;
            i0 = take ? (j0 + u) : i0;
        }
    }
    int* op = idx + (size_t)(base + i_local) * NK;
    op[0]=base+i0; op[1]=base+i1; op[2]=base+i2; op[3]=base+i3;
    op[4]=base+i4; op[5]=base+i5; op[6]=base+i6;
}

// ---------------- 2: feat1 — x(16) -> qv1[n][128], ks1[n][128] (interleaved) ----------------
__global__ __launch_bounds__(256) void feat1_kernel(
    const float* __restrict__ x,
    const float* __restrict__ wk, const float* __restrict__ bk,
    const float* __restrict__ wq, const float* __restrict__ bq,
    const float* __restrict__ wv, const float* __restrict__ bv,
    const float* __restrict__ wsm, const float* __restrict__ bs,
    unsigned short* __restrict__ qv, unsigned short* __restrict__ ks) {
    int c = threadIdx.x & 63;
    float Wk[16], Wq[16], Wv[16], Ws[16];
    #pragma unroll
    for (int k = 0; k < 16; ++k) {
        Wk[k] = wk[k*64+c]; Wq[k] = wq[k*64+c]; Wv[k] = wv[k*64+c]; Ws[k] = wsm[k*64+c];
    }
    float Bk = bk[c], Bq = bq[c], Bv = bv[c], Bs = bs[c];
    int wave = blockIdx.x * (blockDim.x >> 6) + (threadIdx.x >> 6);
    int nw   = gridDim.x * (blockDim.x >> 6);
    for (int n = wave; n < NNODES; n += nw) {
        const float* xr = x + (size_t)n * 16;
        float ak = Bk, aq = Bq, av = Bv, as = Bs;
        #pragma unroll
        for (int k = 0; k < 16; ++k) {
            float xv = xr[k];
            ak += xv * Wk[k]; aq += xv * Wq[k]; av += xv * Wv[k]; as += xv * Ws[k];
        }
        size_t o = (size_t)n * 128 + c;
        qv[o] = f2bf(aq); qv[o + 64] = f2bf(av);
        ks[o] = f2bf(ak); ks[o + 64] = f2bf(as);
    }
}

// ---------------- 3: gated conv — interleaved qv gathers, XCD-swizzled ----------------
// qv layout: [n][2C] (q at +0, v at +C); ks layout: [n][2C] (k at +0, s at +C)
template<int C>
__global__ __launch_bounds__(256) void conv_kernel(
    const unsigned short* __restrict__ qv, const unsigned short* __restrict__ ks,
    const int* __restrict__ idx, unsigned short* __restrict__ h) {
    const int NPB = 256 / C;
    int c   = threadIdx.x & (C - 1);
    int sub = threadIdx.x / C;
    int b     = blockIdx.x;            // 4096 total = 128 graphs x 32
    int xcd   = b & 7;
    int chunk = b >> 3;                // 0..511
    int graph = xcd * 16 + (chunk >> 5);
    int nblk  = chunk & 31;
    int n0 = graph * NPER + nblk * 32;
    for (int i = sub; i < 32; i += NPB) {
        int n = n0 + i;
        const int* nb = idx + (size_t)n * NK;
        size_t o = (size_t)n * 2 * C + c;
        float kv  = bf2f(ks[o]);
        float acc = bf2f(ks[o + C]);
        #pragma unroll
        for (int k = 0; k < NK; ++k) {
            int j = nb[k];
            size_t jo = (size_t)j * 2 * C + c;
            float qvv = bf2f(qv[jo]);
            float vvv = bf2f(qv[jo + C]);
            float t = kv + qvv;
            float s = 1.f / (1.f + __expf(-t));
            acc += s * vvv;
        }
        h[(size_t)n * C + c] = f2bf(acc);
    }
}

// ---------------- 4: BN stats (deterministic two-stage) ----------------
template<int C>
__global__ __launch_bounds__(256) void bn_stats_kernel(const unsigned short* __restrict__ h,
                                                       float* __restrict__ part) {
    const int LPB = 256 / C;
    int c = threadIdx.x & (C - 1);
    int sub = threadIdx.x / C;
    const int nodesPer = NNODES / 256;
    int n0 = blockIdx.x * nodesPer;
    float s = 0.f, s2 = 0.f;
    for (int i = sub; i < nodesPer; i += LPB) {
        float v = bf2f(h[(size_t)(n0 + i) * C + c]);
        s += v; s2 += v * v;
    }
    __shared__ float ls[256], ls2[256];
    ls[threadIdx.x] = s; ls2[threadIdx.x] = s2;
    __syncthreads();
    if (threadIdx.x < C) {
        #pragma unroll
        for (int l = 1; l < LPB; ++l) { s += ls[threadIdx.x + l*C]; s2 += ls2[threadIdx.x + l*C]; }
        part[(size_t)blockIdx.x * 2 * C + c]     = s;
        part[(size_t)blockIdx.x * 2 * C + C + c] = s2;
    }
}

__global__ void bn_finalize_kernel(const float* __restrict__ part,
                                   const float* __restrict__ gamma, const float* __restrict__ beta,
                                   float* __restrict__ ss, int C) {
    int c = threadIdx.x;
    if (c >= C) return;
    float s = 0.f, s2 = 0.f;
    for (int b = 0; b < 256; ++b) { s += part[(size_t)b*2*C + c]; s2 += part[(size_t)b*2*C + C + c]; }
    float m   = s / (float)NNODES;
    float var = s2 / (float)NNODES - m * m;
    float inv = rsqrtf(var + 1e-5f);
    float sc  = gamma[c] * inv;
    ss[c]     = sc;
    ss[C + c] = beta[c] - m * sc;
}

// ---------------- 6: bf16 MFMA B-fragments for the 4 layer-2 weights ----------------
__global__ __launch_bounds__(64) void wfrag_kernel(
    const float* __restrict__ w0, const float* __restrict__ w1,
    const float* __restrict__ w2, const float* __restrict__ w3,
    unsigned short* __restrict__ frag) {
    int m  = blockIdx.x >> 4;
    int kt = (blockIdx.x >> 3) & 1;
    int ct = blockIdx.x & 7;
    const float* w = (m == 0) ? w0 : (m == 1) ? w1 : (m == 2) ? w2 : w3;
    int l = threadIdx.x;
    int col = ct * 16 + (l & 15);
    int kbase = kt * 32 + (l >> 4) * 8;
    unsigned short* out = frag + ((size_t)blockIdx.x * 64 + l) * 8;
    #pragma unroll
    for (int e = 0; e < 8; ++e) out[e] = f2bf(w[(size_t)(kbase + e) * 128 + col]);
}

// ---------------- 7: feat2 — fused BN1+ReLU on load, MFMA, interleaved outputs ----------------
// m=0:k -> ks2+0, m=1:q -> qv2+0, m=2:v -> qv2+128, m=3:s -> ks2+128 (stride 256)
__global__ __launch_bounds__(256) void feat2_kernel(
    const unsigned short* __restrict__ h1n, const unsigned short* __restrict__ frag,
    const float* __restrict__ ss1,
    const float* __restrict__ b0, const float* __restrict__ b1,
    const float* __restrict__ b2, const float* __restrict__ b3,
    unsigned short* __restrict__ qv2, unsigned short* __restrict__ ks2) {
    int nt = blockIdx.x;
    int m  = threadIdx.x >> 6;
    int l  = threadIdx.x & 63;
    const float* bm    = (m == 0) ? b0 : (m == 1) ? b1 : (m == 2) ? b2 : b3;
    unsigned short* om = (m == 1 || m == 2) ? qv2 : ks2;
    int oofs           = (m >= 2) ? 128 : 0;
    int lr = l & 15;
    int gq = l >> 4;
    int n  = nt * 16 + lr;
    const unsigned short* ar = h1n + (size_t)n * 64 + gq * 8;
    short8 a0r = *(const short8*)ar;
    short8 a1r = *(const short8*)(ar + 32);
    short8 a0, a1;
    #pragma unroll
    for (int e = 0; e < 8; ++e) {
        int c0 = gq * 8 + e;
        float f0 = bf2f((unsigned short)a0r[e]) * ss1[c0] + ss1[64 + c0];
        a0[e] = (short)f2bf(fmaxf(f0, 0.f));
        int c1 = 32 + gq * 8 + e;
        float f1 = bf2f((unsigned short)a1r[e]) * ss1[c1] + ss1[64 + c1];
        a1[e] = (short)f2bf(fmaxf(f1, 0.f));
    }
    #pragma unroll
    for (int ct = 0; ct < 8; ++ct) {
        size_t fb0 = ((size_t)(m * 16 + ct)     * 64 + l) * 8;
        size_t fb1 = ((size_t)(m * 16 + 8 + ct) * 64 + l) * 8;
        short8 w0 = *(const short8*)(frag + fb0);
        short8 w1 = *(const short8*)(frag + fb1);
        float bv = bm[ct * 16 + lr];
        floatx4 acc = {bv, bv, bv, bv};
        acc = __builtin_amdgcn_mfma_f32_16x16x32_bf16(a0, w0, acc, 0, 0, 0);
        acc = __builtin_amdgcn_mfma_f32_16x16x32_bf16(a1, w1, acc, 0, 0, 0);
        int ocol = ct * 16 + lr;
        #pragma unroll
        for (int r = 0; r < 4; ++r) {
            int orow = nt * 16 + gq * 4 + r;
            om[(size_t)orow * 256 + oofs + ocol] = f2bf(acc[r]);
        }
    }
}

// ---------------- 8: mean-pool with fused BN2+ReLU, two-stage ----------------
__global__ __launch_bounds__(256) void pool_partial_kernel(const unsigned short* __restrict__ h2,
                                                           const float* __restrict__ ss2,
                                                           float* __restrict__ part) {
    int g = blockIdx.x >> 2;
    int q = blockIdx.x & 3;
    int c = threadIdx.x & 127;
    int isub = threadIdx.x >> 7;  // 0..1
    float sc = ss2[c], sh = ss2[128 + c];
    float acc = 0.f;
    const unsigned short* hp = h2 + ((size_t)g * NPER + q * 256) * 128;
    for (int i = isub; i < 256; i += 2)
        acc += fmaxf(bf2f(hp[(size_t)i * 128 + c]) * sc + sh, 0.f);
    __shared__ float red[256];
    red[threadIdx.x] = acc;
    __syncthreads();
    if (threadIdx.x < 128)
        part[(size_t)blockIdx.x * 128 + c] = acc + red[threadIdx.x + 128];
}

__global__ void pool_final_kernel(const float* __restrict__ part, float* __restrict__ out) {
    int g = blockIdx.x, c = threadIdx.x;
    float s = part[(size_t)(g*4+0)*128+c] + part[(size_t)(g*4+1)*128+c]
            + part[(size_t)(g*4+2)*128+c] + part[(size_t)(g*4+3)*128+c];
    out[(size_t)g * 128 + c] = s * (1.f / 1024.f);
}

extern "C" void kernel_launch(void* const* d_in, const int* in_sizes, int n_in,
                              void* d_out, int out_size, void* d_ws, size_t ws_size,
                              hipStream_t stream) {
    const float* x   = (const float*)d_in[0];
    const float* pos = (const float*)d_in[1];
    const float* wk1 = (const float*)d_in[3];
    const float* bk1 = (const float*)d_in[4];
    const float* wq1 = (const float*)d_in[5];
    const float* bq1 = (const float*)d_in[6];
    const float* wv1 = (const float*)d_in[7];
    const float* bv1 = (const float*)d_in[8];
    const float* ws1 = (const float*)d_in[9];
    const float* bs1 = (const float*)d_in[10];
    const float* g1  = (const float*)d_in[11];
    const float* be1 = (const float*)d_in[12];
    const float* wk2 = (const float*)d_in[13];
    const float* bk2 = (const float*)d_in[14];
    const float* wq2 = (const float*)d_in[15];
    const float* bq2 = (const float*)d_in[16];
    const float* wv2 = (const float*)d_in[17];
    const float* bv2 = (const float*)d_in[18];
    const float* ws2 = (const float*)d_in[19];
    const float* bs2 = (const float*)d_in[20];
    const float* g2  = (const float*)d_in[21];
    const float* be2 = (const float*)d_in[22];
    float* out = (float*)d_out;

    const size_t SZ_QV1 = (size_t)NNODES * 128 * 2;  // 32 MiB
    const size_t SZ_QV2 = (size_t)NNODES * 256 * 2;  // 64 MiB

    char* ws = (char*)d_ws;
    size_t off = 0;
    auto alloc = [&](size_t b) { size_t o = off; off += (b + 255) & ~(size_t)255; return o; };

    int* idx              = (int*)(ws + alloc((size_t)NNODES * NK * 4));
    size_t o_region       = alloc(2 * SZ_QV2);      // layer-2 qv/ks; layer-1 aliased in front
    unsigned short* qv1   = (unsigned short*)(ws + o_region);
    unsigned short* ks1   = (unsigned short*)(ws + o_region + SZ_QV1);
    unsigned short* qv2   = (unsigned short*)(ws + o_region);
    unsigned short* ks2   = (unsigned short*)(ws + o_region + SZ_QV2);
    unsigned short* h1    = (unsigned short*)(ws + alloc((size_t)NNODES * 64 * 2));
    unsigned short* h2    = (unsigned short*)(ws + alloc((size_t)NNODES * 128 * 2));
    unsigned short* frag  = (unsigned short*)(ws + alloc(64 * 64 * 8 * 2));
    float* part           = (float*)(ws + alloc(512 * 128 * 4));
    float* ss1            = (float*)(ws + alloc(2 * 64 * 4));
    float* ss2            = (float*)(ws + alloc(2 * 128 * 4));
    (void)ws_size; (void)in_sizes; (void)n_in; (void)out_size;

    knn_kernel<<<BGR * 4, 256, 0, stream>>>(pos, idx);
    feat1_kernel<<<1024, 256, 0, stream>>>(x, wk1, bk1, wq1, bq1, wv1, bv1, ws1, bs1,
                                           qv1, ks1);
    conv_kernel<64><<<NNODES / 32, 256, 0, stream>>>(qv1, ks1, idx, h1);
    bn_stats_kernel<64><<<256, 256, 0, stream>>>(h1, part);
    bn_finalize_kernel<<<1, 64, 0, stream>>>(part, g1, be1, ss1, 64);
    wfrag_kernel<<<64, 64, 0, stream>>>(wk2, wq2, wv2, ws2, frag);
    feat2_kernel<<<NNODES / 16, 256, 0, stream>>>(h1, frag, ss1, bk2, bq2, bv2, bs2,
                                                  qv2, ks2);
    conv_kernel<128><<<NNODES / 32, 256, 0, stream>>>(qv2, ks2, idx, h2);
    bn_stats_kernel<128><<<256, 256, 0, stream>>>(h2, part);
    bn_finalize_kernel<<<1, 128, 0, stream>>>(part, g2, be2, ss2, 128);
    pool_partial_kernel<<<BGR * 4, 256, 0, stream>>>(h2, ss2, part);
    pool_final_kernel<<<BGR, 128, 0, stream>>>(part, out);
}

// Round 5
// 456.066 us; speedup vs baseline: 1.2290x; 1.0820x over previous
//
#include <hip/hip_runtime.h>
#include <hip/hip_bf16.h>

#define BGR   128
#define NPER  1024
#define NK    7
#define NNODES (BGR*NPER)

typedef __attribute__((ext_vector_type(8))) short short8;
typedef __attribute__((ext_vector_type(8))) unsigned short ushort8;
typedef __attribute__((ext_vector_type(4))) float floatx4;

static __device__ __forceinline__ float bf2f(unsigned short u) {
    unsigned int x = ((unsigned int)u) << 16;
    return __builtin_bit_cast(float, x);
}
static __device__ __forceinline__ unsigned short f2bf(float f) {
    unsigned int x = __builtin_bit_cast(unsigned int, f);
    unsigned int lsb = (x >> 16) & 1u;
    x += 0x7fffu + lsb;
    return (unsigned short)(x >> 16);
}

// ---------------- 1: kNN — branchless two-pass; pass1 top-7 via med3 chain ----------------
// Insert into sorted top-7: new b_k = med3(b_{k-1}, b_k, t)  (single v_med3_f32 each,
// all 6 independent), b0 = min(b0,t). Pass2 recomputes d bit-identically and collects
// indices with a branchless cndmask shift register.
__global__ __launch_bounds__(256) void knn_kernel(const float* __restrict__ pos,
                                                  int* __restrict__ idx) {
    __shared__ __align__(16) float xs[NPER];
    __shared__ __align__(16) float ys[NPER];
    __shared__ __align__(16) float zs[NPER];
    int g = blockIdx.x >> 2;
    int i_local = ((blockIdx.x & 3) << 8) + threadIdx.x;
    int base = g * NPER;
    const float* pg = pos + (size_t)base * 3;
    for (int t = threadIdx.x; t < NPER * 3; t += 256) {
        float v = pg[t];
        int j = t / 3, comp = t - j * 3;
        if (comp == 0) xs[j] = v; else if (comp == 1) ys[j] = v; else zs[j] = v;
    }
    __syncthreads();
    float mex = xs[i_local], mey = ys[i_local], mez = zs[i_local];

    // pass 1: values only, fully branchless, med3 insert
    float b0=3e38f,b1=3e38f,b2=3e38f,b3=3e38f,b4=3e38f,b5=3e38f,b6=3e38f;
    for (int j0 = 0; j0 < NPER; j0 += 8) {
        floatx4 xa = *(const floatx4*)&xs[j0], xb = *(const floatx4*)&xs[j0+4];
        floatx4 ya = *(const floatx4*)&ys[j0], yb = *(const floatx4*)&ys[j0+4];
        floatx4 za = *(const floatx4*)&zs[j0], zb = *(const floatx4*)&zs[j0+4];
        #pragma unroll
        for (int u = 0; u < 8; ++u) {
            float qx = (u < 4) ? xa[u] : xb[u-4];
            float qy = (u < 4) ? ya[u] : yb[u-4];
            float qz = (u < 4) ? za[u] : zb[u-4];
            float dx = mex-qx, dy = mey-qy, dz = mez-qz;
            float d = fmaf(dx,dx, fmaf(dy,dy, dz*dz));
            float t = (j0 + u == i_local) ? 3e38f : d;
            float n6 = __builtin_amdgcn_fmed3f(b5, b6, t);
            float n5 = __builtin_amdgcn_fmed3f(b4, b5, t);
            float n4 = __builtin_amdgcn_fmed3f(b3, b4, t);
            float n3 = __builtin_amdgcn_fmed3f(b2, b3, t);
            float n2 = __builtin_amdgcn_fmed3f(b1, b2, t);
            float n1 = __builtin_amdgcn_fmed3f(b0, b1, t);
            b0 = fminf(b0, t);
            b1 = n1; b2 = n2; b3 = n3; b4 = n4; b5 = n5; b6 = n6;
        }
    }

    // pass 2: branchless index collection (d <= b6 selects exactly the top-7)
    int i0=0,i1=0,i2=0,i3=0,i4=0,i5=0,i6=0;
    for (int j0 = 0; j0 < NPER; j0 += 8) {
        floatx4 xa = *(const floatx4*)&xs[j0], xb = *(const floatx4*)&xs[j0+4];
        floatx4 ya = *(const floatx4*)&ys[j0], yb = *(const floatx4*)&ys[j0+4];
        floatx4 za = *(const floatx4*)&zs[j0], zb = *(const floatx4*)&zs[j0+4];
        #pragma unroll
        for (int u = 0; u < 8; ++u) {
            float qx = (u < 4) ? xa[u] : xb[u-4];
            float qy = (u < 4) ? ya[u] : yb[u-4];
            float qz = (u < 4) ? za[u] : zb[u-4];
            float dx = mex-qx, dy = mey-qy, dz = mez-qz;
            float d = fmaf(dx,dx, fmaf(dy,dy, dz*dz));
            bool take = (d <= b6) && (j0 + u != i_local);
            i6 = take ? i5 : i6;
            i5 = take ? i4 : i5;
            i4 = take ? i3 : i4;
            i3 = take ? i2 : i3;
            i2 = take ? i1 : i2;
            i1 = take ? i0 : i1;
            i0 = take ? (j0 + u) : i0;
        }
    }
    int* op = idx + (size_t)(base + i_local) * NK;
    op[0]=base+i0; op[1]=base+i1; op[2]=base+i2; op[3]=base+i3;
    op[4]=base+i4; op[5]=base+i5; op[6]=base+i6;
}

// ---------------- 2: feat1 — x(16) -> qv1[n][128], ks1[n][128] (interleaved) ----------------
__global__ __launch_bounds__(256) void feat1_kernel(
    const float* __restrict__ x,
    const float* __restrict__ wk, const float* __restrict__ bk,
    const float* __restrict__ wq, const float* __restrict__ bq,
    const float* __restrict__ wv, const float* __restrict__ bv,
    const float* __restrict__ wsm, const float* __restrict__ bs,
    unsigned short* __restrict__ qv, unsigned short* __restrict__ ks) {
    int c = threadIdx.x & 63;
    float Wk[16], Wq[16], Wv[16], Ws[16];
    #pragma unroll
    for (int k = 0; k < 16; ++k) {
        Wk[k] = wk[k*64+c]; Wq[k] = wq[k*64+c]; Wv[k] = wv[k*64+c]; Ws[k] = wsm[k*64+c];
    }
    float Bk = bk[c], Bq = bq[c], Bv = bv[c], Bs = bs[c];
    int wave = blockIdx.x * (blockDim.x >> 6) + (threadIdx.x >> 6);
    int nw   = gridDim.x * (blockDim.x >> 6);
    for (int n = wave; n < NNODES; n += nw) {
        const float* xr = x + (size_t)n * 16;
        float ak = Bk, aq = Bq, av = Bv, as = Bs;
        #pragma unroll
        for (int k = 0; k < 16; ++k) {
            float xv = xr[k];
            ak += xv * Wk[k]; aq += xv * Wq[k]; av += xv * Wv[k]; as += xv * Ws[k];
        }
        size_t o = (size_t)n * 128 + c;
        qv[o] = f2bf(aq); qv[o + 64] = f2bf(av);
        ks[o] = f2bf(ak); ks[o + 64] = f2bf(as);
    }
}

// ---------------- 3: gated conv — interleaved qv gathers, XCD-swizzled ----------------
// qv layout: [n][2C] (q at +0, v at +C); ks layout: [n][2C] (k at +0, s at +C)
template<int C>
__global__ __launch_bounds__(256) void conv_kernel(
    const unsigned short* __restrict__ qv, const unsigned short* __restrict__ ks,
    const int* __restrict__ idx, unsigned short* __restrict__ h) {
    const int NPB = 256 / C;
    int c   = threadIdx.x & (C - 1);
    int sub = threadIdx.x / C;
    int b     = blockIdx.x;            // 4096 total = 128 graphs x 32
    int xcd   = b & 7;
    int chunk = b >> 3;                // 0..511
    int graph = xcd * 16 + (chunk >> 5);
    int nblk  = chunk & 31;
    int n0 = graph * NPER + nblk * 32;
    #pragma unroll 2
    for (int i = sub; i < 32; i += NPB) {
        int n = n0 + i;
        const int* nb = idx + (size_t)n * NK;
        size_t o = (size_t)n * 2 * C + c;
        float kv  = bf2f(ks[o]);
        float acc = bf2f(ks[o + C]);
        #pragma unroll
        for (int k = 0; k < NK; ++k) {
            int j = nb[k];
            size_t jo = (size_t)j * 2 * C + c;
            float qvv = bf2f(qv[jo]);
            float vvv = bf2f(qv[jo + C]);
            float t = kv + qvv;
            float s = 1.f / (1.f + __expf(-t));
            acc += s * vvv;
        }
        h[(size_t)n * C + c] = f2bf(acc);
    }
}

// ---------------- 4: BN stats (deterministic two-stage) ----------------
template<int C>
__global__ __launch_bounds__(256) void bn_stats_kernel(const unsigned short* __restrict__ h,
                                                       float* __restrict__ part) {
    const int LPB = 256 / C;
    int c = threadIdx.x & (C - 1);
    int sub = threadIdx.x / C;
    const int nodesPer = NNODES / 256;
    int n0 = blockIdx.x * nodesPer;
    float s = 0.f, s2 = 0.f;
    for (int i = sub; i < nodesPer; i += LPB) {
        float v = bf2f(h[(size_t)(n0 + i) * C + c]);
        s += v; s2 += v * v;
    }
    __shared__ float ls[256], ls2[256];
    ls[threadIdx.x] = s; ls2[threadIdx.x] = s2;
    __syncthreads();
    if (threadIdx.x < C) {
        #pragma unroll
        for (int l = 1; l < LPB; ++l) { s += ls[threadIdx.x + l*C]; s2 += ls2[threadIdx.x + l*C]; }
        part[(size_t)blockIdx.x * 2 * C + c]     = s;
        part[(size_t)blockIdx.x * 2 * C + C + c] = s2;
    }
}

static __device__ __forceinline__ void bn_finalize_body(
    const float* __restrict__ part, const float* __restrict__ gamma,
    const float* __restrict__ beta, float* __restrict__ ss, int C, int c) {
    float s = 0.f, s2 = 0.f;
    for (int b = 0; b < 256; ++b) { s += part[(size_t)b*2*C + c]; s2 += part[(size_t)b*2*C + C + c]; }
    float m   = s / (float)NNODES;
    float var = s2 / (float)NNODES - m * m;
    float inv = rsqrtf(var + 1e-5f);
    float sc  = gamma[c] * inv;
    ss[c]     = sc;
    ss[C + c] = beta[c] - m * sc;
}

__global__ void bn_finalize_kernel(const float* __restrict__ part,
                                   const float* __restrict__ gamma, const float* __restrict__ beta,
                                   float* __restrict__ ss, int C) {
    int c = threadIdx.x;
    if (c >= C) return;
    bn_finalize_body(part, gamma, beta, ss, C, c);
}

// ---------------- 5: merged bn_finalize(64) + wfrag (saves a launch) ----------------
// block 0: finalize layer-1 BN; blocks 1..64: build bf16 MFMA B-fragments
// slot = m*16 + kt*8 + ct ; lane l supplies col=ct*16+(l&15), k=kt*32+(l>>4)*8+e
__global__ __launch_bounds__(64) void fin1_wfrag_kernel(
    const float* __restrict__ part, const float* __restrict__ gamma,
    const float* __restrict__ beta, float* __restrict__ ss,
    const float* __restrict__ w0, const float* __restrict__ w1,
    const float* __restrict__ w2, const float* __restrict__ w3,
    unsigned short* __restrict__ frag) {
    if (blockIdx.x == 0) {
        bn_finalize_body(part, gamma, beta, ss, 64, threadIdx.x);
        return;
    }
    int s  = blockIdx.x - 1;
    int m  = s >> 4;
    int kt = (s >> 3) & 1;
    int ct = s & 7;
    const float* w = (m == 0) ? w0 : (m == 1) ? w1 : (m == 2) ? w2 : w3;
    int l = threadIdx.x;
    int col = ct * 16 + (l & 15);
    int kbase = kt * 32 + (l >> 4) * 8;
    unsigned short* out = frag + ((size_t)s * 64 + l) * 8;
    #pragma unroll
    for (int e = 0; e < 8; ++e) out[e] = f2bf(w[(size_t)(kbase + e) * 128 + col]);
}

// ---------------- 7: feat2 — fused BN1+ReLU on load, MFMA, interleaved outputs ----------------
// m=0:k -> ks2+0, m=1:q -> qv2+0, m=2:v -> qv2+128, m=3:s -> ks2+128 (stride 256)
__global__ __launch_bounds__(256) void feat2_kernel(
    const unsigned short* __restrict__ h1n, const unsigned short* __restrict__ frag,
    const float* __restrict__ ss1,
    const float* __restrict__ b0, const float* __restrict__ b1,
    const float* __restrict__ b2, const float* __restrict__ b3,
    unsigned short* __restrict__ qv2, unsigned short* __restrict__ ks2) {
    int nt = blockIdx.x;
    int m  = threadIdx.x >> 6;
    int l  = threadIdx.x & 63;
    const float* bm    = (m == 0) ? b0 : (m == 1) ? b1 : (m == 2) ? b2 : b3;
    unsigned short* om = (m == 1 || m == 2) ? qv2 : ks2;
    int oofs           = (m >= 2) ? 128 : 0;
    int lr = l & 15;
    int gq = l >> 4;
    int n  = nt * 16 + lr;
    const unsigned short* ar = h1n + (size_t)n * 64 + gq * 8;
    short8 a0r = *(const short8*)ar;
    short8 a1r = *(const short8*)(ar + 32);
    short8 a0, a1;
    #pragma unroll
    for (int e = 0; e < 8; ++e) {
        int c0 = gq * 8 + e;
        float f0 = bf2f((unsigned short)a0r[e]) * ss1[c0] + ss1[64 + c0];
        a0[e] = (short)f2bf(fmaxf(f0, 0.f));
        int c1 = 32 + gq * 8 + e;
        float f1 = bf2f((unsigned short)a1r[e]) * ss1[c1] + ss1[64 + c1];
        a1[e] = (short)f2bf(fmaxf(f1, 0.f));
    }
    #pragma unroll
    for (int ct = 0; ct < 8; ++ct) {
        size_t fb0 = ((size_t)(m * 16 + ct)     * 64 + l) * 8;
        size_t fb1 = ((size_t)(m * 16 + 8 + ct) * 64 + l) * 8;
        short8 w0 = *(const short8*)(frag + fb0);
        short8 w1 = *(const short8*)(frag + fb1);
        float bv = bm[ct * 16 + lr];
        floatx4 acc = {bv, bv, bv, bv};
        acc = __builtin_amdgcn_mfma_f32_16x16x32_bf16(a0, w0, acc, 0, 0, 0);
        acc = __builtin_amdgcn_mfma_f32_16x16x32_bf16(a1, w1, acc, 0, 0, 0);
        int ocol = ct * 16 + lr;
        #pragma unroll
        for (int r = 0; r < 4; ++r) {
            int orow = nt * 16 + gq * 4 + r;
            om[(size_t)orow * 256 + oofs + ocol] = f2bf(acc[r]);
        }
    }
}

// ---------------- 8: mean-pool with fused BN2+ReLU, two-stage ----------------
__global__ __launch_bounds__(256) void pool_partial_kernel(const unsigned short* __restrict__ h2,
                                                           const float* __restrict__ ss2,
                                                           float* __restrict__ part) {
    int g = blockIdx.x >> 2;
    int q = blockIdx.x & 3;
    int c = threadIdx.x & 127;
    int isub = threadIdx.x >> 7;  // 0..1
    float sc = ss2[c], sh = ss2[128 + c];
    float acc = 0.f;
    const unsigned short* hp = h2 + ((size_t)g * NPER + q * 256) * 128;
    for (int i = isub; i < 256; i += 2)
        acc += fmaxf(bf2f(hp[(size_t)i * 128 + c]) * sc + sh, 0.f);
    __shared__ float red[256];
    red[threadIdx.x] = acc;
    __syncthreads();
    if (threadIdx.x < 128)
        part[(size_t)blockIdx.x * 128 + c] = acc + red[threadIdx.x + 128];
}

__global__ void pool_final_kernel(const float* __restrict__ part, float* __restrict__ out) {
    int g = blockIdx.x, c = threadIdx.x;
    float s = part[(size_t)(g*4+0)*128+c] + part[(size_t)(g*4+1)*128+c]
            + part[(size_t)(g*4+2)*128+c] + part[(size_t)(g*4+3)*128+c];
    out[(size_t)g * 128 + c] = s * (1.f / 1024.f);
}

extern "C" void kernel_launch(void* const* d_in, const int* in_sizes, int n_in,
                              void* d_out, int out_size, void* d_ws, size_t ws_size,
                              hipStream_t stream) {
    const float* x   = (const float*)d_in[0];
    const float* pos = (const float*)d_in[1];
    const float* wk1 = (const float*)d_in[3];
    const float* bk1 = (const float*)d_in[4];
    const float* wq1 = (const float*)d_in[5];
    const float* bq1 = (const float*)d_in[6];
    const float* wv1 = (const float*)d_in[7];
    const float* bv1 = (const float*)d_in[8];
    const float* ws1 = (const float*)d_in[9];
    const float* bs1 = (const float*)d_in[10];
    const float* g1  = (const float*)d_in[11];
    const float* be1 = (const float*)d_in[12];
    const float* wk2 = (const float*)d_in[13];
    const float* bk2 = (const float*)d_in[14];
    const float* wq2 = (const float*)d_in[15];
    const float* bq2 = (const float*)d_in[16];
    const float* wv2 = (const float*)d_in[17];
    const float* bv2 = (const float*)d_in[18];
    const float* ws2 = (const float*)d_in[19];
    const float* bs2 = (const float*)d_in[20];
    const float* g2  = (const float*)d_in[21];
    const float* be2 = (const float*)d_in[22];
    float* out = (float*)d_out;

    const size_t SZ_QV1 = (size_t)NNODES * 128 * 2;  // 32 MiB
    const size_t SZ_QV2 = (size_t)NNODES * 256 * 2;  // 64 MiB

    char* ws = (char*)d_ws;
    size_t off = 0;
    auto alloc = [&](size_t b) { size_t o = off; off += (b + 255) & ~(size_t)255; return o; };

    int* idx              = (int*)(ws + alloc((size_t)NNODES * NK * 4));
    size_t o_region       = alloc(2 * SZ_QV2);      // layer-2 qv/ks; layer-1 aliased in front
    unsigned short* qv1   = (unsigned short*)(ws + o_region);
    unsigned short* ks1   = (unsigned short*)(ws + o_region + SZ_QV1);
    unsigned short* qv2   = (unsigned short*)(ws + o_region);
    unsigned short* ks2   = (unsigned short*)(ws + o_region + SZ_QV2);
    unsigned short* h1    = (unsigned short*)(ws + alloc((size_t)NNODES * 64 * 2));
    unsigned short* h2    = (unsigned short*)(ws + alloc((size_t)NNODES * 128 * 2));
    unsigned short* frag  = (unsigned short*)(ws + alloc(64 * 64 * 8 * 2));
    float* part           = (float*)(ws + alloc(512 * 128 * 4));
    float* ss1            = (float*)(ws + alloc(2 * 64 * 4));
    float* ss2            = (float*)(ws + alloc(2 * 128 * 4));
    (void)ws_size; (void)in_sizes; (void)n_in; (void)out_size;

    knn_kernel<<<BGR * 4, 256, 0, stream>>>(pos, idx);
    feat1_kernel<<<1024, 256, 0, stream>>>(x, wk1, bk1, wq1, bq1, wv1, bv1, ws1, bs1,
                                           qv1, ks1);
    conv_kernel<64><<<NNODES / 32, 256, 0, stream>>>(qv1, ks1, idx, h1);
    bn_stats_kernel<64><<<256, 256, 0, stream>>>(h1, part);
    fin1_wfrag_kernel<<<65, 64, 0, stream>>>(part, g1, be1, ss1,
                                             wk2, wq2, wv2, ws2, frag);
    feat2_kernel<<<NNODES / 16, 256, 0, stream>>>(h1, frag, ss1, bk2, bq2, bv2, bs2,
                                                  qv2, ks2);
    conv_kernel<128><<<NNODES / 32, 256, 0, stream>>>(qv2, ks2, idx, h2);
    bn_stats_kernel<128><<<256, 256, 0, stream>>>(h2, part);
    bn_finalize_kernel<<<1, 128, 0, stream>>>(part, g2, be2, ss2, 128);
    pool_partial_kernel<<<BGR * 4, 256, 0, stream>>>(h2, ss2, part);
    pool_final_kernel<<<BGR, 128, 0, stream>>>(part, out);
}

// Round 6
// 330.145 us; speedup vs baseline: 1.6977x; 1.3814x over previous
//
#include <hip/hip_runtime.h>
#include <hip/hip_bf16.h>

#define BGR   128
#define NPER  1024
#define NK    7
#define NNODES (BGR*NPER)

typedef __attribute__((ext_vector_type(8))) short short8;
typedef __attribute__((ext_vector_type(8))) unsigned short ushort8;
typedef __attribute__((ext_vector_type(4))) float floatx4;

static __device__ __forceinline__ float bf2f(unsigned short u) {
    unsigned int x = ((unsigned int)u) << 16;
    return __builtin_bit_cast(float, x);
}
static __device__ __forceinline__ unsigned short f2bf(float f) {
    unsigned int x = __builtin_bit_cast(unsigned int, f);
    unsigned int lsb = (x >> 16) & 1u;
    x += 0x7fffu + lsb;
    return (unsigned short)(x >> 16);
}

// ---------------- 1: kNN — ONE-PASS branchless, index packed in mantissa LSBs ----------------
// packed = (bits(d) & ~1023) | j ; positive-float bit order == value order, so the
// med3 insert chain sorts (quantized-distance, index) pairs directly. No second pass.
__global__ __launch_bounds__(256) void knn_kernel(const float* __restrict__ pos,
                                                  int* __restrict__ idx) {
    __shared__ __align__(16) float xs[NPER];
    __shared__ __align__(16) float ys[NPER];
    __shared__ __align__(16) float zs[NPER];
    int g = blockIdx.x >> 2;
    int i_local = ((blockIdx.x & 3) << 8) + threadIdx.x;
    int base = g * NPER;
    const float* pg = pos + (size_t)base * 3;
    for (int t = threadIdx.x; t < NPER * 3; t += 256) {
        float v = pg[t];
        int j = t / 3, comp = t - j * 3;
        if (comp == 0) xs[j] = v; else if (comp == 1) ys[j] = v; else zs[j] = v;
    }
    __syncthreads();
    float mex = xs[i_local], mey = ys[i_local], mez = zs[i_local];

    float b0=3e38f,b1=3e38f,b2=3e38f,b3=3e38f,b4=3e38f,b5=3e38f,b6=3e38f;
    for (int j0 = 0; j0 < NPER; j0 += 8) {
        floatx4 xa = *(const floatx4*)&xs[j0], xb = *(const floatx4*)&xs[j0+4];
        floatx4 ya = *(const floatx4*)&ys[j0], yb = *(const floatx4*)&ys[j0+4];
        floatx4 za = *(const floatx4*)&zs[j0], zb = *(const floatx4*)&zs[j0+4];
        #pragma unroll
        for (int u = 0; u < 8; ++u) {
            float qx = (u < 4) ? xa[u] : xb[u-4];
            float qy = (u < 4) ? ya[u] : yb[u-4];
            float qz = (u < 4) ? za[u] : zb[u-4];
            float dx = mex-qx, dy = mey-qy, dz = mez-qz;
            float d = fmaf(dx,dx, fmaf(dy,dy, dz*dz));
            d = (j0 + u == i_local) ? 3e38f : d;
            unsigned int ub = (__builtin_bit_cast(unsigned int, d) & 0xFFFFFC00u)
                              | (unsigned int)(j0 + u);
            float t = __builtin_bit_cast(float, ub);
            float n6 = __builtin_amdgcn_fmed3f(b5, b6, t);
            float n5 = __builtin_amdgcn_fmed3f(b4, b5, t);
            float n4 = __builtin_amdgcn_fmed3f(b3, b4, t);
            float n3 = __builtin_amdgcn_fmed3f(b2, b3, t);
            float n2 = __builtin_amdgcn_fmed3f(b1, b2, t);
            float n1 = __builtin_amdgcn_fmed3f(b0, b1, t);
            b0 = fminf(b0, t);
            b1 = n1; b2 = n2; b3 = n3; b4 = n4; b5 = n5; b6 = n6;
        }
    }
    int* op = idx + (size_t)(base + i_local) * NK;
    op[0] = base + (int)(__builtin_bit_cast(unsigned int, b0) & 1023u);
    op[1] = base + (int)(__builtin_bit_cast(unsigned int, b1) & 1023u);
    op[2] = base + (int)(__builtin_bit_cast(unsigned int, b2) & 1023u);
    op[3] = base + (int)(__builtin_bit_cast(unsigned int, b3) & 1023u);
    op[4] = base + (int)(__builtin_bit_cast(unsigned int, b4) & 1023u);
    op[5] = base + (int)(__builtin_bit_cast(unsigned int, b5) & 1023u);
    op[6] = base + (int)(__builtin_bit_cast(unsigned int, b6) & 1023u);
}

// ---------------- 2: feat1 — x(16) -> packed qv1/ks1 uint[n][64] (lo=q/k, hi=v/s) ----------------
__global__ __launch_bounds__(256) void feat1_kernel(
    const float* __restrict__ x,
    const float* __restrict__ wk, const float* __restrict__ bk,
    const float* __restrict__ wq, const float* __restrict__ bq,
    const float* __restrict__ wv, const float* __restrict__ bv,
    const float* __restrict__ wsm, const float* __restrict__ bs,
    unsigned int* __restrict__ qv, unsigned int* __restrict__ ks) {
    int c = threadIdx.x & 63;
    float Wk[16], Wq[16], Wv[16], Ws[16];
    #pragma unroll
    for (int k = 0; k < 16; ++k) {
        Wk[k] = wk[k*64+c]; Wq[k] = wq[k*64+c]; Wv[k] = wv[k*64+c]; Ws[k] = wsm[k*64+c];
    }
    float Bk = bk[c], Bq = bq[c], Bv = bv[c], Bs = bs[c];
    int wave = blockIdx.x * (blockDim.x >> 6) + (threadIdx.x >> 6);
    int nw   = gridDim.x * (blockDim.x >> 6);
    for (int n = wave; n < NNODES; n += nw) {
        const float* xr = x + (size_t)n * 16;
        float ak = Bk, aq = Bq, av = Bv, as = Bs;
        #pragma unroll
        for (int k = 0; k < 16; ++k) {
            float xv = xr[k];
            ak += xv * Wk[k]; aq += xv * Wq[k]; av += xv * Wv[k]; as += xv * Ws[k];
        }
        size_t o = (size_t)n * 64 + c;
        qv[o] = ((unsigned int)f2bf(av) << 16) | f2bf(aq);
        ks[o] = ((unsigned int)f2bf(as) << 16) | f2bf(ak);
    }
}

// ---------------- 3: gated conv — packed dword gathers + fused BN partial sums ----------------
// qv[n][C] uint: lo16=q, hi16=v ; ks[n][C] uint: lo16=k, hi16=s
template<int C>
__global__ __launch_bounds__(256) void conv_kernel(
    const unsigned int* __restrict__ qv, const unsigned int* __restrict__ ks,
    const int* __restrict__ idx, unsigned short* __restrict__ h,
    float* __restrict__ part) {
    const int NPB = 256 / C;
    int c   = threadIdx.x & (C - 1);
    int sub = threadIdx.x / C;
    int b     = blockIdx.x;            // 4096 total = 128 graphs x 32
    int xcd   = b & 7;
    int chunk = b >> 3;
    int graph = xcd * 16 + (chunk >> 5);
    int nblk  = chunk & 31;
    int n0 = graph * NPER + nblk * 32;
    float s = 0.f, s2 = 0.f;
    #pragma unroll 2
    for (int i = sub; i < 32; i += NPB) {
        int n = n0 + i;
        const int* nb = idx + (size_t)n * NK;
        unsigned int ku = ks[(size_t)n * C + c];
        float kv  = bf2f((unsigned short)(ku & 0xFFFF));
        float acc = bf2f((unsigned short)(ku >> 16));
        #pragma unroll
        for (int k = 0; k < NK; ++k) {
            int j = nb[k];
            unsigned int u = qv[(size_t)j * C + c];
            float qvv = bf2f((unsigned short)(u & 0xFFFF));
            float vvv = bf2f((unsigned short)(u >> 16));
            float t = kv + qvv;
            float sg = 1.f / (1.f + __expf(-t));
            acc += sg * vvv;
        }
        unsigned short hb = f2bf(acc);
        h[(size_t)n * C + c] = hb;
        float hv = bf2f(hb);
        s += hv; s2 += hv * hv;
    }
    __shared__ float ls[256], ls2[256];
    ls[threadIdx.x] = s; ls2[threadIdx.x] = s2;
    __syncthreads();
    if (threadIdx.x < C) {
        #pragma unroll
        for (int l = 1; l < NPB; ++l) { s += ls[threadIdx.x + l*C]; s2 += ls2[threadIdx.x + l*C]; }
        part[(size_t)blockIdx.x * 2 * C + threadIdx.x]     = s;
        part[(size_t)blockIdx.x * 2 * C + C + threadIdx.x] = s2;
    }
}

// ---------------- 4: BN finalize over 4096 block-partials (one block per channel) ----------------
template<int C>
static __device__ __forceinline__ void bnfin_body(
    const float* __restrict__ part, const float* __restrict__ gamma,
    const float* __restrict__ beta, float* __restrict__ ss,
    int c, float* ls, float* ls2) {
    float s = 0.f, s2 = 0.f;
    for (int b = threadIdx.x; b < 4096; b += 256) {
        s  += part[(size_t)b * 2 * C + c];
        s2 += part[(size_t)b * 2 * C + C + c];
    }
    ls[threadIdx.x] = s; ls2[threadIdx.x] = s2;
    __syncthreads();
    for (int st = 128; st > 0; st >>= 1) {
        if (threadIdx.x < st) { ls[threadIdx.x] += ls[threadIdx.x+st]; ls2[threadIdx.x] += ls2[threadIdx.x+st]; }
        __syncthreads();
    }
    if (threadIdx.x == 0) {
        float m   = ls[0] / (float)NNODES;
        float var = ls2[0] / (float)NNODES - m * m;
        float inv = rsqrtf(var + 1e-5f);
        float sc  = gamma[c] * inv;
        ss[c]     = sc;
        ss[C + c] = beta[c] - m * sc;
    }
}

template<int C>
__global__ __launch_bounds__(256) void bnfin_kernel(
    const float* __restrict__ part, const float* __restrict__ gamma,
    const float* __restrict__ beta, float* __restrict__ ss) {
    __shared__ float ls[256], ls2[256];
    bnfin_body<C>(part, gamma, beta, ss, blockIdx.x, ls, ls2);
}

// ---------------- 5: merged BN1-finalize (blocks 0..63) + wfrag (blocks 64..127) ----------------
// wfrag: slot = m*16 + kt*8 + ct ; lane l supplies col=ct*16+(l&15), k=kt*32+(l>>4)*8+e
__global__ __launch_bounds__(256) void fin1_wfrag_kernel(
    const float* __restrict__ part, const float* __restrict__ gamma,
    const float* __restrict__ beta, float* __restrict__ ss,
    const float* __restrict__ w0, const float* __restrict__ w1,
    const float* __restrict__ w2, const float* __restrict__ w3,
    unsigned short* __restrict__ frag) {
    __shared__ float ls[256], ls2[256];
    if (blockIdx.x < 64) {
        bnfin_body<64>(part, gamma, beta, ss, blockIdx.x, ls, ls2);
        return;
    }
    int s  = blockIdx.x - 64;
    if (threadIdx.x >= 64) return;
    int m  = s >> 4;
    int kt = (s >> 3) & 1;
    int ct = s & 7;
    const float* w = (m == 0) ? w0 : (m == 1) ? w1 : (m == 2) ? w2 : w3;
    int l = threadIdx.x;
    int col = ct * 16 + (l & 15);
    int kbase = kt * 32 + (l >> 4) * 8;
    unsigned short* out = frag + ((size_t)s * 64 + l) * 8;
    #pragma unroll
    for (int e = 0; e < 8; ++e) out[e] = f2bf(w[(size_t)(kbase + e) * 128 + col]);
}

// ---------------- 7: feat2 — fused BN1+ReLU on load, MFMA, packed-half outputs ----------------
// m=0:k -> ks2 lo, m=1:q -> qv2 lo, m=2:v -> qv2 hi, m=3:s -> ks2 hi
__global__ __launch_bounds__(256) void feat2_kernel(
    const unsigned short* __restrict__ h1n, const unsigned short* __restrict__ frag,
    const float* __restrict__ ss1,
    const float* __restrict__ b0, const float* __restrict__ b1,
    const float* __restrict__ b2, const float* __restrict__ b3,
    unsigned int* __restrict__ qv2, unsigned int* __restrict__ ks2) {
    int nt = blockIdx.x;
    int m  = threadIdx.x >> 6;
    int l  = threadIdx.x & 63;
    const float* bm     = (m == 0) ? b0 : (m == 1) ? b1 : (m == 2) ? b2 : b3;
    unsigned short* om  = (unsigned short*)((m == 1 || m == 2) ? qv2 : ks2);
    int half            = (m >= 2) ? 1 : 0;
    int lr = l & 15;
    int gq = l >> 4;
    int n  = nt * 16 + lr;
    const unsigned short* ar = h1n + (size_t)n * 64 + gq * 8;
    short8 a0r = *(const short8*)ar;
    short8 a1r = *(const short8*)(ar + 32);
    short8 a0, a1;
    #pragma unroll
    for (int e = 0; e < 8; ++e) {
        int c0 = gq * 8 + e;
        float f0 = bf2f((unsigned short)a0r[e]) * ss1[c0] + ss1[64 + c0];
        a0[e] = (short)f2bf(fmaxf(f0, 0.f));
        int c1 = 32 + gq * 8 + e;
        float f1 = bf2f((unsigned short)a1r[e]) * ss1[c1] + ss1[64 + c1];
        a1[e] = (short)f2bf(fmaxf(f1, 0.f));
    }
    #pragma unroll
    for (int ct = 0; ct < 8; ++ct) {
        size_t fb0 = ((size_t)(m * 16 + ct)     * 64 + l) * 8;
        size_t fb1 = ((size_t)(m * 16 + 8 + ct) * 64 + l) * 8;
        short8 w0 = *(const short8*)(frag + fb0);
        short8 w1 = *(const short8*)(frag + fb1);
        float bv = bm[ct * 16 + lr];
        floatx4 acc = {bv, bv, bv, bv};
        acc = __builtin_amdgcn_mfma_f32_16x16x32_bf16(a0, w0, acc, 0, 0, 0);
        acc = __builtin_amdgcn_mfma_f32_16x16x32_bf16(a1, w1, acc, 0, 0, 0);
        int ocol = ct * 16 + lr;
        #pragma unroll
        for (int r = 0; r < 4; ++r) {
            int orow = nt * 16 + gq * 4 + r;
            om[((size_t)orow * 128 + ocol) * 2 + half] = f2bf(acc[r]);
        }
    }
}

// ---------------- 8: mean-pool with fused BN2+ReLU, two-stage ----------------
__global__ __launch_bounds__(256) void pool_partial_kernel(const unsigned short* __restrict__ h2,
                                                           const float* __restrict__ ss2,
                                                           float* __restrict__ part) {
    int g = blockIdx.x >> 2;
    int q = blockIdx.x & 3;
    int c = threadIdx.x & 127;
    int isub = threadIdx.x >> 7;  // 0..1
    float sc = ss2[c], sh = ss2[128 + c];
    float acc = 0.f;
    const unsigned short* hp = h2 + ((size_t)g * NPER + q * 256) * 128;
    for (int i = isub; i < 256; i += 2)
        acc += fmaxf(bf2f(hp[(size_t)i * 128 + c]) * sc + sh, 0.f);
    __shared__ float red[256];
    red[threadIdx.x] = acc;
    __syncthreads();
    if (threadIdx.x < 128)
        part[(size_t)blockIdx.x * 128 + c] = acc + red[threadIdx.x + 128];
}

__global__ void pool_final_kernel(const float* __restrict__ part, float* __restrict__ out) {
    int g = blockIdx.x, c = threadIdx.x;
    float s = part[(size_t)(g*4+0)*128+c] + part[(size_t)(g*4+1)*128+c]
            + part[(size_t)(g*4+2)*128+c] + part[(size_t)(g*4+3)*128+c];
    out[(size_t)g * 128 + c] = s * (1.f / 1024.f);
}

extern "C" void kernel_launch(void* const* d_in, const int* in_sizes, int n_in,
                              void* d_out, int out_size, void* d_ws, size_t ws_size,
                              hipStream_t stream) {
    const float* x   = (const float*)d_in[0];
    const float* pos = (const float*)d_in[1];
    const float* wk1 = (const float*)d_in[3];
    const float* bk1 = (const float*)d_in[4];
    const float* wq1 = (const float*)d_in[5];
    const float* bq1 = (const float*)d_in[6];
    const float* wv1 = (const float*)d_in[7];
    const float* bv1 = (const float*)d_in[8];
    const float* ws1 = (const float*)d_in[9];
    const float* bs1 = (const float*)d_in[10];
    const float* g1  = (const float*)d_in[11];
    const float* be1 = (const float*)d_in[12];
    const float* wk2 = (const float*)d_in[13];
    const float* bk2 = (const float*)d_in[14];
    const float* wq2 = (const float*)d_in[15];
    const float* bq2 = (const float*)d_in[16];
    const float* wv2 = (const float*)d_in[17];
    const float* bv2 = (const float*)d_in[18];
    const float* ws2 = (const float*)d_in[19];
    const float* bs2 = (const float*)d_in[20];
    const float* g2  = (const float*)d_in[21];
    const float* be2 = (const float*)d_in[22];
    float* out = (float*)d_out;

    const size_t SZ_QV1 = (size_t)NNODES * 64 * 4;   // 32 MiB (uint[n][64])
    const size_t SZ_QV2 = (size_t)NNODES * 128 * 4;  // 64 MiB (uint[n][128])

    char* ws = (char*)d_ws;
    size_t off = 0;
    auto alloc = [&](size_t b) { size_t o = off; off += (b + 255) & ~(size_t)255; return o; };

    int* idx              = (int*)(ws + alloc((size_t)NNODES * NK * 4));
    size_t o_region       = alloc(2 * SZ_QV2);      // layer-2 qv/ks; layer-1 aliased in front
    unsigned int* qv1     = (unsigned int*)(ws + o_region);
    unsigned int* ks1     = (unsigned int*)(ws + o_region + SZ_QV1);
    unsigned int* qv2     = (unsigned int*)(ws + o_region);
    unsigned int* ks2     = (unsigned int*)(ws + o_region + SZ_QV2);
    unsigned short* h1    = (unsigned short*)(ws + alloc((size_t)NNODES * 64 * 2));
    unsigned short* h2    = (unsigned short*)(ws + alloc((size_t)NNODES * 128 * 2));
    unsigned short* frag  = (unsigned short*)(ws + alloc(64 * 64 * 8 * 2));
    float* part           = (float*)(ws + alloc((size_t)4096 * 2 * 128 * 4));
    float* ss1            = (float*)(ws + alloc(2 * 64 * 4));
    float* ss2            = (float*)(ws + alloc(2 * 128 * 4));
    (void)ws_size; (void)in_sizes; (void)n_in; (void)out_size;

    knn_kernel<<<BGR * 4, 256, 0, stream>>>(pos, idx);
    feat1_kernel<<<1024, 256, 0, stream>>>(x, wk1, bk1, wq1, bq1, wv1, bv1, ws1, bs1,
                                           qv1, ks1);
    conv_kernel<64><<<NNODES / 32, 256, 0, stream>>>(qv1, ks1, idx, h1, part);
    fin1_wfrag_kernel<<<128, 256, 0, stream>>>(part, g1, be1, ss1,
                                               wk2, wq2, wv2, ws2, frag);
    feat2_kernel<<<NNODES / 16, 256, 0, stream>>>(h1, frag, ss1, bk2, bq2, bv2, bs2,
                                                  qv2, ks2);
    conv_kernel<128><<<NNODES / 32, 256, 0, stream>>>(qv2, ks2, idx, h2, part);
    bnfin_kernel<128><<<128, 256, 0, stream>>>(part, g2, be2, ss2);
    pool_partial_kernel<<<BGR * 4, 256, 0, stream>>>(h2, ss2, part);
    pool_final_kernel<<<BGR, 128, 0, stream>>>(part, out);
}

// Round 7
// 323.067 us; speedup vs baseline: 1.7349x; 1.0219x over previous
//
#include <hip/hip_runtime.h>
#include <hip/hip_bf16.h>

#define BGR   128
#define NPER  1024
#define NK    7
#define NNODES (BGR*NPER)

typedef __attribute__((ext_vector_type(8))) short short8;
typedef __attribute__((ext_vector_type(8))) unsigned short ushort8;
typedef __attribute__((ext_vector_type(4))) float floatx4;

static __device__ __forceinline__ float bf2f(unsigned short u) {
    unsigned int x = ((unsigned int)u) << 16;
    return __builtin_bit_cast(float, x);
}
static __device__ __forceinline__ unsigned short f2bf(float f) {
    unsigned int x = __builtin_bit_cast(unsigned int, f);
    unsigned int lsb = (x >> 16) & 1u;
    x += 0x7fffu + lsb;
    return (unsigned short)(x >> 16);
}

// ---------------- 1: kNN — ONE-PASS branchless, index packed in mantissa LSBs ----------------
__global__ __launch_bounds__(256) void knn_kernel(const float* __restrict__ pos,
                                                  int* __restrict__ idx) {
    __shared__ __align__(16) float xs[NPER];
    __shared__ __align__(16) float ys[NPER];
    __shared__ __align__(16) float zs[NPER];
    int g = blockIdx.x >> 2;
    int i_local = ((blockIdx.x & 3) << 8) + threadIdx.x;
    int base = g * NPER;
    const float* pg = pos + (size_t)base * 3;
    for (int t = threadIdx.x; t < NPER * 3; t += 256) {
        float v = pg[t];
        int j = t / 3, comp = t - j * 3;
        if (comp == 0) xs[j] = v; else if (comp == 1) ys[j] = v; else zs[j] = v;
    }
    __syncthreads();
    float mex = xs[i_local], mey = ys[i_local], mez = zs[i_local];

    float b0=3e38f,b1=3e38f,b2=3e38f,b3=3e38f,b4=3e38f,b5=3e38f,b6=3e38f;
    for (int j0 = 0; j0 < NPER; j0 += 8) {
        floatx4 xa = *(const floatx4*)&xs[j0], xb = *(const floatx4*)&xs[j0+4];
        floatx4 ya = *(const floatx4*)&ys[j0], yb = *(const floatx4*)&ys[j0+4];
        floatx4 za = *(const floatx4*)&zs[j0], zb = *(const floatx4*)&zs[j0+4];
        #pragma unroll
        for (int u = 0; u < 8; ++u) {
            float qx = (u < 4) ? xa[u] : xb[u-4];
            float qy = (u < 4) ? ya[u] : yb[u-4];
            float qz = (u < 4) ? za[u] : zb[u-4];
            float dx = mex-qx, dy = mey-qy, dz = mez-qz;
            float d = fmaf(dx,dx, fmaf(dy,dy, dz*dz));
            d = (j0 + u == i_local) ? 3e38f : d;
            unsigned int ub = (__builtin_bit_cast(unsigned int, d) & 0xFFFFFC00u)
                              | (unsigned int)(j0 + u);
            float t = __builtin_bit_cast(float, ub);
            float n6 = __builtin_amdgcn_fmed3f(b5, b6, t);
            float n5 = __builtin_amdgcn_fmed3f(b4, b5, t);
            float n4 = __builtin_amdgcn_fmed3f(b3, b4, t);
            float n3 = __builtin_amdgcn_fmed3f(b2, b3, t);
            float n2 = __builtin_amdgcn_fmed3f(b1, b2, t);
            float n1 = __builtin_amdgcn_fmed3f(b0, b1, t);
            b0 = fminf(b0, t);
            b1 = n1; b2 = n2; b3 = n3; b4 = n4; b5 = n5; b6 = n6;
        }
    }
    int* op = idx + (size_t)(base + i_local) * NK;
    op[0] = base + (int)(__builtin_bit_cast(unsigned int, b0) & 1023u);
    op[1] = base + (int)(__builtin_bit_cast(unsigned int, b1) & 1023u);
    op[2] = base + (int)(__builtin_bit_cast(unsigned int, b2) & 1023u);
    op[3] = base + (int)(__builtin_bit_cast(unsigned int, b3) & 1023u);
    op[4] = base + (int)(__builtin_bit_cast(unsigned int, b4) & 1023u);
    op[5] = base + (int)(__builtin_bit_cast(unsigned int, b5) & 1023u);
    op[6] = base + (int)(__builtin_bit_cast(unsigned int, b6) & 1023u);
}

// ---------------- 2: feat1 — x(16) -> packed qv1/ks1 uint[n][64] (lo=q/k, hi=v/s) ----------------
__global__ __launch_bounds__(256) void feat1_kernel(
    const float* __restrict__ x,
    const float* __restrict__ wk, const float* __restrict__ bk,
    const float* __restrict__ wq, const float* __restrict__ bq,
    const float* __restrict__ wv, const float* __restrict__ bv,
    const float* __restrict__ wsm, const float* __restrict__ bs,
    unsigned int* __restrict__ qv, unsigned int* __restrict__ ks) {
    int c = threadIdx.x & 63;
    float Wk[16], Wq[16], Wv[16], Ws[16];
    #pragma unroll
    for (int k = 0; k < 16; ++k) {
        Wk[k] = wk[k*64+c]; Wq[k] = wq[k*64+c]; Wv[k] = wv[k*64+c]; Ws[k] = wsm[k*64+c];
    }
    float Bk = bk[c], Bq = bq[c], Bv = bv[c], Bs = bs[c];
    int wave = blockIdx.x * (blockDim.x >> 6) + (threadIdx.x >> 6);
    int nw   = gridDim.x * (blockDim.x >> 6);
    for (int n = wave; n < NNODES; n += nw) {
        const float* xr = x + (size_t)n * 16;
        float ak = Bk, aq = Bq, av = Bv, as = Bs;
        #pragma unroll
        for (int k = 0; k < 16; ++k) {
            float xv = xr[k];
            ak += xv * Wk[k]; aq += xv * Wq[k]; av += xv * Wv[k]; as += xv * Ws[k];
        }
        size_t o = (size_t)n * 64 + c;
        qv[o] = ((unsigned int)f2bf(av) << 16) | f2bf(aq);
        ks[o] = ((unsigned int)f2bf(as) << 16) | f2bf(ak);
    }
}

// ---------------- 3: gated conv — SCALAR (wave-uniform) addressing via readfirstlane ----------------
// Each wave owns one node's channel slice, so node index and all 7 neighbor indices are
// wave-uniform -> force them into SGPRs; gathers become s[base] + v_off(c*4) loads with
// zero per-lane address VALU. qv[n][C] uint: lo16=q, hi16=v ; ks[n][C]: lo16=k, hi16=s.
template<int C>
__global__ __launch_bounds__(256) void conv_kernel(
    const unsigned int* __restrict__ qv, const unsigned int* __restrict__ ks,
    const int* __restrict__ idx, unsigned short* __restrict__ h,
    float* __restrict__ part) {
    const int NPB = 256 / C;
    int c   = threadIdx.x & (C - 1);
    int sub = __builtin_amdgcn_readfirstlane((int)(threadIdx.x / C));
    int b     = blockIdx.x;            // 4096 total = 128 graphs x 32
    int xcd   = b & 7;
    int chunk = b >> 3;
    int graph = xcd * 16 + (chunk >> 5);
    int nblk  = chunk & 31;
    int n0 = graph * NPER + nblk * 32;
    float s = 0.f, s2 = 0.f;
    #pragma unroll 2
    for (int i = sub; i < 32; i += NPB) {
        int n = n0 + i;                // wave-uniform (sub is SGPR)
        const int* nb = idx + (size_t)n * NK;
        unsigned int ku = ks[(size_t)n * C + c];
        float kv  = bf2f((unsigned short)(ku & 0xFFFF));
        float acc = bf2f((unsigned short)(ku >> 16));
        #pragma unroll
        for (int k = 0; k < NK; ++k) {
            int j = __builtin_amdgcn_readfirstlane(nb[k]);   // SGPR neighbor index
            const unsigned int* p = qv + (size_t)j * C;      // SGPR base
            unsigned int u = p[c];                           // s[base] + v_off load
            float qvv = bf2f((unsigned short)(u & 0xFFFF));
            float vvv = bf2f((unsigned short)(u >> 16));
            float t = kv + qvv;
            float sg = 1.f / (1.f + __expf(-t));
            acc += sg * vvv;
        }
        unsigned short hb = f2bf(acc);
        h[(size_t)n * C + c] = hb;
        float hv = bf2f(hb);
        s += hv; s2 += hv * hv;
    }
    __shared__ float ls[256], ls2[256];
    ls[threadIdx.x] = s; ls2[threadIdx.x] = s2;
    __syncthreads();
    if (threadIdx.x < C) {
        #pragma unroll
        for (int l = 1; l < NPB; ++l) { s += ls[threadIdx.x + l*C]; s2 += ls2[threadIdx.x + l*C]; }
        part[(size_t)blockIdx.x * 2 * C + threadIdx.x]     = s;
        part[(size_t)blockIdx.x * 2 * C + C + threadIdx.x] = s2;
    }
}

// ---------------- 4: BN finalize over 4096 block-partials (one block per channel) ----------------
template<int C>
static __device__ __forceinline__ void bnfin_body(
    const float* __restrict__ part, const float* __restrict__ gamma,
    const float* __restrict__ beta, float* __restrict__ ss,
    int c, float* ls, float* ls2) {
    float s = 0.f, s2 = 0.f;
    for (int b = threadIdx.x; b < 4096; b += 256) {
        s  += part[(size_t)b * 2 * C + c];
        s2 += part[(size_t)b * 2 * C + C + c];
    }
    ls[threadIdx.x] = s; ls2[threadIdx.x] = s2;
    __syncthreads();
    for (int st = 128; st > 0; st >>= 1) {
        if (threadIdx.x < st) { ls[threadIdx.x] += ls[threadIdx.x+st]; ls2[threadIdx.x] += ls2[threadIdx.x+st]; }
        __syncthreads();
    }
    if (threadIdx.x == 0) {
        float m   = ls[0] / (float)NNODES;
        float var = ls2[0] / (float)NNODES - m * m;
        float inv = rsqrtf(var + 1e-5f);
        float sc  = gamma[c] * inv;
        ss[c]     = sc;
        ss[C + c] = beta[c] - m * sc;
    }
}

template<int C>
__global__ __launch_bounds__(256) void bnfin_kernel(
    const float* __restrict__ part, const float* __restrict__ gamma,
    const float* __restrict__ beta, float* __restrict__ ss) {
    __shared__ float ls[256], ls2[256];
    bnfin_body<C>(part, gamma, beta, ss, blockIdx.x, ls, ls2);
}

// ---------------- 5: merged BN1-finalize (blocks 0..63) + wfrag (blocks 64..127) ----------------
__global__ __launch_bounds__(256) void fin1_wfrag_kernel(
    const float* __restrict__ part, const float* __restrict__ gamma,
    const float* __restrict__ beta, float* __restrict__ ss,
    const float* __restrict__ w0, const float* __restrict__ w1,
    const float* __restrict__ w2, const float* __restrict__ w3,
    unsigned short* __restrict__ frag) {
    __shared__ float ls[256], ls2[256];
    if (blockIdx.x < 64) {
        bnfin_body<64>(part, gamma, beta, ss, blockIdx.x, ls, ls2);
        return;
    }
    int s  = blockIdx.x - 64;
    if (threadIdx.x >= 64) return;
    int m  = s >> 4;
    int kt = (s >> 3) & 1;
    int ct = s & 7;
    const float* w = (m == 0) ? w0 : (m == 1) ? w1 : (m == 2) ? w2 : w3;
    int l = threadIdx.x;
    int col = ct * 16 + (l & 15);
    int kbase = kt * 32 + (l >> 4) * 8;
    unsigned short* out = frag + ((size_t)s * 64 + l) * 8;
    #pragma unroll
    for (int e = 0; e < 8; ++e) out[e] = f2bf(w[(size_t)(kbase + e) * 128 + col]);
}

// ---------------- 7: feat2 — fused BN1+ReLU on load, MFMA, packed-half outputs ----------------
__global__ __launch_bounds__(256) void feat2_kernel(
    const unsigned short* __restrict__ h1n, const unsigned short* __restrict__ frag,
    const float* __restrict__ ss1,
    const float* __restrict__ b0, const float* __restrict__ b1,
    const float* __restrict__ b2, const float* __restrict__ b3,
    unsigned int* __restrict__ qv2, unsigned int* __restrict__ ks2) {
    int nt = blockIdx.x;
    int m  = threadIdx.x >> 6;
    int l  = threadIdx.x & 63;
    const float* bm     = (m == 0) ? b0 : (m == 1) ? b1 : (m == 2) ? b2 : b3;
    unsigned short* om  = (unsigned short*)((m == 1 || m == 2) ? qv2 : ks2);
    int half            = (m >= 2) ? 1 : 0;
    int lr = l & 15;
    int gq = l >> 4;
    int n  = nt * 16 + lr;
    const unsigned short* ar = h1n + (size_t)n * 64 + gq * 8;
    short8 a0r = *(const short8*)ar;
    short8 a1r = *(const short8*)(ar + 32);
    short8 a0, a1;
    #pragma unroll
    for (int e = 0; e < 8; ++e) {
        int c0 = gq * 8 + e;
        float f0 = bf2f((unsigned short)a0r[e]) * ss1[c0] + ss1[64 + c0];
        a0[e] = (short)f2bf(fmaxf(f0, 0.f));
        int c1 = 32 + gq * 8 + e;
        float f1 = bf2f((unsigned short)a1r[e]) * ss1[c1] + ss1[64 + c1];
        a1[e] = (short)f2bf(fmaxf(f1, 0.f));
    }
    #pragma unroll
    for (int ct = 0; ct < 8; ++ct) {
        size_t fb0 = ((size_t)(m * 16 + ct)     * 64 + l) * 8;
        size_t fb1 = ((size_t)(m * 16 + 8 + ct) * 64 + l) * 8;
        short8 w0 = *(const short8*)(frag + fb0);
        short8 w1 = *(const short8*)(frag + fb1);
        float bv = bm[ct * 16 + lr];
        floatx4 acc = {bv, bv, bv, bv};
        acc = __builtin_amdgcn_mfma_f32_16x16x32_bf16(a0, w0, acc, 0, 0, 0);
        acc = __builtin_amdgcn_mfma_f32_16x16x32_bf16(a1, w1, acc, 0, 0, 0);
        int ocol = ct * 16 + lr;
        #pragma unroll
        for (int r = 0; r < 4; ++r) {
            int orow = nt * 16 + gq * 4 + r;
            om[((size_t)orow * 128 + ocol) * 2 + half] = f2bf(acc[r]);
        }
    }
}

// ---------------- 8: mean-pool with fused BN2+ReLU, two-stage ----------------
__global__ __launch_bounds__(256) void pool_partial_kernel(const unsigned short* __restrict__ h2,
                                                           const float* __restrict__ ss2,
                                                           float* __restrict__ part) {
    int g = blockIdx.x >> 2;
    int q = blockIdx.x & 3;
    int c = threadIdx.x & 127;
    int isub = threadIdx.x >> 7;  // 0..1
    float sc = ss2[c], sh = ss2[128 + c];
    float acc = 0.f;
    const unsigned short* hp = h2 + ((size_t)g * NPER + q * 256) * 128;
    for (int i = isub; i < 256; i += 2)
        acc += fmaxf(bf2f(hp[(size_t)i * 128 + c]) * sc + sh, 0.f);
    __shared__ float red[256];
    red[threadIdx.x] = acc;
    __syncthreads();
    if (threadIdx.x < 128)
        part[(size_t)blockIdx.x * 128 + c] = acc + red[threadIdx.x + 128];
}

__global__ void pool_final_kernel(const float* __restrict__ part, float* __restrict__ out) {
    int g = blockIdx.x, c = threadIdx.x;
    float s = part[(size_t)(g*4+0)*128+c] + part[(size_t)(g*4+1)*128+c]
            + part[(size_t)(g*4+2)*128+c] + part[(size_t)(g*4+3)*128+c];
    out[(size_t)g * 128 + c] = s * (1.f / 1024.f);
}

extern "C" void kernel_launch(void* const* d_in, const int* in_sizes, int n_in,
                              void* d_out, int out_size, void* d_ws, size_t ws_size,
                              hipStream_t stream) {
    const float* x   = (const float*)d_in[0];
    const float* pos = (const float*)d_in[1];
    const float* wk1 = (const float*)d_in[3];
    const float* bk1 = (const float*)d_in[4];
    const float* wq1 = (const float*)d_in[5];
    const float* bq1 = (const float*)d_in[6];
    const float* wv1 = (const float*)d_in[7];
    const float* bv1 = (const float*)d_in[8];
    const float* ws1 = (const float*)d_in[9];
    const float* bs1 = (const float*)d_in[10];
    const float* g1  = (const float*)d_in[11];
    const float* be1 = (const float*)d_in[12];
    const float* wk2 = (const float*)d_in[13];
    const float* bk2 = (const float*)d_in[14];
    const float* wq2 = (const float*)d_in[15];
    const float* bq2 = (const float*)d_in[16];
    const float* wv2 = (const float*)d_in[17];
    const float* bv2 = (const float*)d_in[18];
    const float* ws2 = (const float*)d_in[19];
    const float* bs2 = (const float*)d_in[20];
    const float* g2  = (const float*)d_in[21];
    const float* be2 = (const float*)d_in[22];
    float* out = (float*)d_out;

    const size_t SZ_QV1 = (size_t)NNODES * 64 * 4;   // 32 MiB (uint[n][64])
    const size_t SZ_QV2 = (size_t)NNODES * 128 * 4;  // 64 MiB (uint[n][128])

    char* ws = (char*)d_ws;
    size_t off = 0;
    auto alloc = [&](size_t b) { size_t o = off; off += (b + 255) & ~(size_t)255; return o; };

    int* idx              = (int*)(ws + alloc((size_t)NNODES * NK * 4));
    size_t o_region       = alloc(2 * SZ_QV2);      // layer-2 qv/ks; layer-1 aliased in front
    unsigned int* qv1     = (unsigned int*)(ws + o_region);
    unsigned int* ks1     = (unsigned int*)(ws + o_region + SZ_QV1);
    unsigned int* qv2     = (unsigned int*)(ws + o_region);
    unsigned int* ks2     = (unsigned int*)(ws + o_region + SZ_QV2);
    unsigned short* h1    = (unsigned short*)(ws + alloc((size_t)NNODES * 64 * 2));
    unsigned short* h2    = (unsigned short*)(ws + alloc((size_t)NNODES * 128 * 2));
    unsigned short* frag  = (unsigned short*)(ws + alloc(64 * 64 * 8 * 2));
    float* part           = (float*)(ws + alloc((size_t)4096 * 2 * 128 * 4));
    float* ss1            = (float*)(ws + alloc(2 * 64 * 4));
    float* ss2            = (float*)(ws + alloc(2 * 128 * 4));
    (void)ws_size; (void)in_sizes; (void)n_in; (void)out_size;

    knn_kernel<<<BGR * 4, 256, 0, stream>>>(pos, idx);
    feat1_kernel<<<1024, 256, 0, stream>>>(x, wk1, bk1, wq1, bq1, wv1, bv1, ws1, bs1,
                                           qv1, ks1);
    conv_kernel<64><<<NNODES / 32, 256, 0, stream>>>(qv1, ks1, idx, h1, part);
    fin1_wfrag_kernel<<<128, 256, 0, stream>>>(part, g1, be1, ss1,
                                               wk2, wq2, wv2, ws2, frag);
    feat2_kernel<<<NNODES / 16, 256, 0, stream>>>(h1, frag, ss1, bk2, bq2, bv2, bs2,
                                                  qv2, ks2);
    conv_kernel<128><<<NNODES / 32, 256, 0, stream>>>(qv2, ks2, idx, h2, part);
    bnfin_kernel<128><<<128, 256, 0, stream>>>(part, g2, be2, ss2);
    pool_partial_kernel<<<BGR * 4, 256, 0, stream>>>(h2, ss2, part);
    pool_final_kernel<<<BGR, 128, 0, stream>>>(part, out);
}

// Round 8
// 289.688 us; speedup vs baseline: 1.9348x; 1.1152x over previous
//
#include <hip/hip_runtime.h>
#include <hip/hip_bf16.h>

#define BGR   128
#define NPER  1024
#define NK    7
#define NNODES (BGR*NPER)

typedef __attribute__((ext_vector_type(8))) short short8;
typedef __attribute__((ext_vector_type(8))) unsigned short ushort8;
typedef __attribute__((ext_vector_type(4))) float floatx4;

static __device__ __forceinline__ float bf2f(unsigned short u) {
    unsigned int x = ((unsigned int)u) << 16;
    return __builtin_bit_cast(float, x);
}
static __device__ __forceinline__ unsigned short f2bf(float f) {
    unsigned int x = __builtin_bit_cast(unsigned int, f);
    unsigned int lsb = (x >> 16) & 1u;
    x += 0x7fffu + lsb;
    return (unsigned short)(x >> 16);
}

// ---------------- 1: kNN — ONE-PASS branchless, index packed in mantissa LSBs ----------------
__global__ __launch_bounds__(256) void knn_kernel(const float* __restrict__ pos,
                                                  int* __restrict__ idx) {
    __shared__ __align__(16) float xs[NPER];
    __shared__ __align__(16) float ys[NPER];
    __shared__ __align__(16) float zs[NPER];
    int g = blockIdx.x >> 2;
    int i_local = ((blockIdx.x & 3) << 8) + threadIdx.x;
    int base = g * NPER;
    const float* pg = pos + (size_t)base * 3;
    for (int t = threadIdx.x; t < NPER * 3; t += 256) {
        float v = pg[t];
        int j = t / 3, comp = t - j * 3;
        if (comp == 0) xs[j] = v; else if (comp == 1) ys[j] = v; else zs[j] = v;
    }
    __syncthreads();
    float mex = xs[i_local], mey = ys[i_local], mez = zs[i_local];

    float b0=3e38f,b1=3e38f,b2=3e38f,b3=3e38f,b4=3e38f,b5=3e38f,b6=3e38f;
    for (int j0 = 0; j0 < NPER; j0 += 8) {
        floatx4 xa = *(const floatx4*)&xs[j0], xb = *(const floatx4*)&xs[j0+4];
        floatx4 ya = *(const floatx4*)&ys[j0], yb = *(const floatx4*)&ys[j0+4];
        floatx4 za = *(const floatx4*)&zs[j0], zb = *(const floatx4*)&zs[j0+4];
        #pragma unroll
        for (int u = 0; u < 8; ++u) {
            float qx = (u < 4) ? xa[u] : xb[u-4];
            float qy = (u < 4) ? ya[u] : yb[u-4];
            float qz = (u < 4) ? za[u] : zb[u-4];
            float dx = mex-qx, dy = mey-qy, dz = mez-qz;
            float d = fmaf(dx,dx, fmaf(dy,dy, dz*dz));
            d = (j0 + u == i_local) ? 3e38f : d;
            unsigned int ub = (__builtin_bit_cast(unsigned int, d) & 0xFFFFFC00u)
                              | (unsigned int)(j0 + u);
            float t = __builtin_bit_cast(float, ub);
            float n6 = __builtin_amdgcn_fmed3f(b5, b6, t);
            float n5 = __builtin_amdgcn_fmed3f(b4, b5, t);
            float n4 = __builtin_amdgcn_fmed3f(b3, b4, t);
            float n3 = __builtin_amdgcn_fmed3f(b2, b3, t);
            float n2 = __builtin_amdgcn_fmed3f(b1, b2, t);
            float n1 = __builtin_amdgcn_fmed3f(b0, b1, t);
            b0 = fminf(b0, t);
            b1 = n1; b2 = n2; b3 = n3; b4 = n4; b5 = n5; b6 = n6;
        }
    }
    int* op = idx + (size_t)(base + i_local) * NK;
    op[0] = base + (int)(__builtin_bit_cast(unsigned int, b0) & 1023u);
    op[1] = base + (int)(__builtin_bit_cast(unsigned int, b1) & 1023u);
    op[2] = base + (int)(__builtin_bit_cast(unsigned int, b2) & 1023u);
    op[3] = base + (int)(__builtin_bit_cast(unsigned int, b3) & 1023u);
    op[4] = base + (int)(__builtin_bit_cast(unsigned int, b4) & 1023u);
    op[5] = base + (int)(__builtin_bit_cast(unsigned int, b5) & 1023u);
    op[6] = base + (int)(__builtin_bit_cast(unsigned int, b6) & 1023u);
}

// ---------------- 2: feat1 — x(16) -> packed qv1/ks1 uint[n][64] (lo=q/k, hi=v/s) ----------------
__global__ __launch_bounds__(256) void feat1_kernel(
    const float* __restrict__ x,
    const float* __restrict__ wk, const float* __restrict__ bk,
    const float* __restrict__ wq, const float* __restrict__ bq,
    const float* __restrict__ wv, const float* __restrict__ bv,
    const float* __restrict__ wsm, const float* __restrict__ bs,
    unsigned int* __restrict__ qv, unsigned int* __restrict__ ks) {
    int c = threadIdx.x & 63;
    float Wk[16], Wq[16], Wv[16], Ws[16];
    #pragma unroll
    for (int k = 0; k < 16; ++k) {
        Wk[k] = wk[k*64+c]; Wq[k] = wq[k*64+c]; Wv[k] = wv[k*64+c]; Ws[k] = wsm[k*64+c];
    }
    float Bk = bk[c], Bq = bq[c], Bv = bv[c], Bs = bs[c];
    int wave = blockIdx.x * (blockDim.x >> 6) + (threadIdx.x >> 6);
    int nw   = gridDim.x * (blockDim.x >> 6);
    for (int n = wave; n < NNODES; n += nw) {
        const float* xr = x + (size_t)n * 16;
        float ak = Bk, aq = Bq, av = Bv, as = Bs;
        #pragma unroll
        for (int k = 0; k < 16; ++k) {
            float xv = xr[k];
            ak += xv * Wk[k]; aq += xv * Wq[k]; av += xv * Wv[k]; as += xv * Ws[k];
        }
        size_t o = (size_t)n * 64 + c;
        qv[o] = ((unsigned int)f2bf(av) << 16) | f2bf(aq);
        ks[o] = ((unsigned int)f2bf(as) << 16) | f2bf(ak);
    }
}

// ---------------- 3: gated conv — scalar addressing + single-instruction rcp sigmoid ----------------
// qv[n][C] uint: lo16=q, hi16=v ; ks[n][C]: lo16=k, hi16=s
template<int C>
__global__ __launch_bounds__(256) void conv_kernel(
    const unsigned int* __restrict__ qv, const unsigned int* __restrict__ ks,
    const int* __restrict__ idx, unsigned short* __restrict__ h,
    float* __restrict__ part) {
    const int NPB = 256 / C;
    int c   = threadIdx.x & (C - 1);
    int sub = __builtin_amdgcn_readfirstlane((int)(threadIdx.x / C));
    int b     = blockIdx.x;            // 4096 total = 128 graphs x 32
    int xcd   = b & 7;
    int chunk = b >> 3;
    int graph = xcd * 16 + (chunk >> 5);
    int nblk  = chunk & 31;
    int n0 = graph * NPER + nblk * 32;
    float s = 0.f, s2 = 0.f;
    #pragma unroll 2
    for (int i = sub; i < 32; i += NPB) {
        int n = n0 + i;                // wave-uniform (sub is SGPR)
        const int* nb = idx + (size_t)n * NK;
        unsigned int ku = ks[(size_t)n * C + c];
        float kv  = bf2f((unsigned short)(ku & 0xFFFF));
        float acc = bf2f((unsigned short)(ku >> 16));
        #pragma unroll
        for (int k = 0; k < NK; ++k) {
            int j = __builtin_amdgcn_readfirstlane(nb[k]);   // SGPR neighbor index
            const unsigned int* p = qv + (size_t)j * C;      // SGPR base
            unsigned int u = p[c];                           // s[base] + v_off load
            float qvv = bf2f((unsigned short)(u & 0xFFFF));
            float vvv = bf2f((unsigned short)(u >> 16));
            float t = kv + qvv;
            float sg = __builtin_amdgcn_rcpf(1.f + __expf(-t));  // v_exp + v_rcp, no IEEE div
            acc = fmaf(sg, vvv, acc);
        }
        unsigned short hb = f2bf(acc);
        h[(size_t)n * C + c] = hb;
        float hv = bf2f(hb);
        s += hv; s2 += hv * hv;
    }
    __shared__ float ls[256], ls2[256];
    ls[threadIdx.x] = s; ls2[threadIdx.x] = s2;
    __syncthreads();
    if (threadIdx.x < C) {
        #pragma unroll
        for (int l = 1; l < NPB; ++l) { s += ls[threadIdx.x + l*C]; s2 += ls2[threadIdx.x + l*C]; }
        part[(size_t)blockIdx.x * 2 * C + threadIdx.x]     = s;
        part[(size_t)blockIdx.x * 2 * C + C + threadIdx.x] = s2;
    }
}

// ---------------- 4: BN finalize over 4096 block-partials (one block per channel) ----------------
template<int C>
static __device__ __forceinline__ void bnfin_body(
    const float* __restrict__ part, const float* __restrict__ gamma,
    const float* __restrict__ beta, float* __restrict__ ss,
    int c, float* ls, float* ls2) {
    float s = 0.f, s2 = 0.f;
    for (int b = threadIdx.x; b < 4096; b += 256) {
        s  += part[(size_t)b * 2 * C + c];
        s2 += part[(size_t)b * 2 * C + C + c];
    }
    ls[threadIdx.x] = s; ls2[threadIdx.x] = s2;
    __syncthreads();
    for (int st = 128; st > 0; st >>= 1) {
        if (threadIdx.x < st) { ls[threadIdx.x] += ls[threadIdx.x+st]; ls2[threadIdx.x] += ls2[threadIdx.x+st]; }
        __syncthreads();
    }
    if (threadIdx.x == 0) {
        float m   = ls[0] / (float)NNODES;
        float var = ls2[0] / (float)NNODES - m * m;
        float inv = rsqrtf(var + 1e-5f);
        float sc  = gamma[c] * inv;
        ss[c]     = sc;
        ss[C + c] = beta[c] - m * sc;
    }
}

template<int C>
__global__ __launch_bounds__(256) void bnfin_kernel(
    const float* __restrict__ part, const float* __restrict__ gamma,
    const float* __restrict__ beta, float* __restrict__ ss) {
    __shared__ float ls[256], ls2[256];
    bnfin_body<C>(part, gamma, beta, ss, blockIdx.x, ls, ls2);
}

// ---------------- 5: merged BN1-finalize (blocks 0..63) + wfrag (blocks 64..127) ----------------
__global__ __launch_bounds__(256) void fin1_wfrag_kernel(
    const float* __restrict__ part, const float* __restrict__ gamma,
    const float* __restrict__ beta, float* __restrict__ ss,
    const float* __restrict__ w0, const float* __restrict__ w1,
    const float* __restrict__ w2, const float* __restrict__ w3,
    unsigned short* __restrict__ frag) {
    __shared__ float ls[256], ls2[256];
    if (blockIdx.x < 64) {
        bnfin_body<64>(part, gamma, beta, ss, blockIdx.x, ls, ls2);
        return;
    }
    int s  = blockIdx.x - 64;
    if (threadIdx.x >= 64) return;
    int m  = s >> 4;
    int kt = (s >> 3) & 1;
    int ct = s & 7;
    const float* w = (m == 0) ? w0 : (m == 1) ? w1 : (m == 2) ? w2 : w3;
    int l = threadIdx.x;
    int col = ct * 16 + (l & 15);
    int kbase = kt * 32 + (l >> 4) * 8;
    unsigned short* out = frag + ((size_t)s * 64 + l) * 8;
    #pragma unroll
    for (int e = 0; e < 8; ++e) out[e] = f2bf(w[(size_t)(kbase + e) * 128 + col]);
}

// ---------------- 7: feat2 — fused BN1+ReLU on load, MFMA, packed-half outputs ----------------
__global__ __launch_bounds__(256) void feat2_kernel(
    const unsigned short* __restrict__ h1n, const unsigned short* __restrict__ frag,
    const float* __restrict__ ss1,
    const float* __restrict__ b0, const float* __restrict__ b1,
    const float* __restrict__ b2, const float* __restrict__ b3,
    unsigned int* __restrict__ qv2, unsigned int* __restrict__ ks2) {
    int nt = blockIdx.x;
    int m  = threadIdx.x >> 6;
    int l  = threadIdx.x & 63;
    const float* bm     = (m == 0) ? b0 : (m == 1) ? b1 : (m == 2) ? b2 : b3;
    unsigned short* om  = (unsigned short*)((m == 1 || m == 2) ? qv2 : ks2);
    int half            = (m >= 2) ? 1 : 0;
    int lr = l & 15;
    int gq = l >> 4;
    int n  = nt * 16 + lr;
    const unsigned short* ar = h1n + (size_t)n * 64 + gq * 8;
    short8 a0r = *(const short8*)ar;
    short8 a1r = *(const short8*)(ar + 32);
    short8 a0, a1;
    #pragma unroll
    for (int e = 0; e < 8; ++e) {
        int c0 = gq * 8 + e;
        float f0 = bf2f((unsigned short)a0r[e]) * ss1[c0] + ss1[64 + c0];
        a0[e] = (short)f2bf(fmaxf(f0, 0.f));
        int c1 = 32 + gq * 8 + e;
        float f1 = bf2f((unsigned short)a1r[e]) * ss1[c1] + ss1[64 + c1];
        a1[e] = (short)f2bf(fmaxf(f1, 0.f));
    }
    #pragma unroll
    for (int ct = 0; ct < 8; ++ct) {
        size_t fb0 = ((size_t)(m * 16 + ct)     * 64 + l) * 8;
        size_t fb1 = ((size_t)(m * 16 + 8 + ct) * 64 + l) * 8;
        short8 w0 = *(const short8*)(frag + fb0);
        short8 w1 = *(const short8*)(frag + fb1);
        float bv = bm[ct * 16 + lr];
        floatx4 acc = {bv, bv, bv, bv};
        acc = __builtin_amdgcn_mfma_f32_16x16x32_bf16(a0, w0, acc, 0, 0, 0);
        acc = __builtin_amdgcn_mfma_f32_16x16x32_bf16(a1, w1, acc, 0, 0, 0);
        int ocol = ct * 16 + lr;
        #pragma unroll
        for (int r = 0; r < 4; ++r) {
            int orow = nt * 16 + gq * 4 + r;
            om[((size_t)orow * 128 + ocol) * 2 + half] = f2bf(acc[r]);
        }
    }
}

// ---------------- 8: mean-pool with fused BN2+ReLU, two-stage ----------------
__global__ __launch_bounds__(256) void pool_partial_kernel(const unsigned short* __restrict__ h2,
                                                           const float* __restrict__ ss2,
                                                           float* __restrict__ part) {
    int g = blockIdx.x >> 2;
    int q = blockIdx.x & 3;
    int c = threadIdx.x & 127;
    int isub = threadIdx.x >> 7;  // 0..1
    float sc = ss2[c], sh = ss2[128 + c];
    float acc = 0.f;
    const unsigned short* hp = h2 + ((size_t)g * NPER + q * 256) * 128;
    for (int i = isub; i < 256; i += 2)
        acc += fmaxf(bf2f(hp[(size_t)i * 128 + c]) * sc + sh, 0.f);
    __shared__ float red[256];
    red[threadIdx.x] = acc;
    __syncthreads();
    if (threadIdx.x < 128)
        part[(size_t)blockIdx.x * 128 + c] = acc + red[threadIdx.x + 128];
}

__global__ void pool_final_kernel(const float* __restrict__ part, float* __restrict__ out) {
    int g = blockIdx.x, c = threadIdx.x;
    float s = part[(size_t)(g*4+0)*128+c] + part[(size_t)(g*4+1)*128+c]
            + part[(size_t)(g*4+2)*128+c] + part[(size_t)(g*4+3)*128+c];
    out[(size_t)g * 128 + c] = s * (1.f / 1024.f);
}

extern "C" void kernel_launch(void* const* d_in, const int* in_sizes, int n_in,
                              void* d_out, int out_size, void* d_ws, size_t ws_size,
                              hipStream_t stream) {
    const float* x   = (const float*)d_in[0];
    const float* pos = (const float*)d_in[1];
    const float* wk1 = (const float*)d_in[3];
    const float* bk1 = (const float*)d_in[4];
    const float* wq1 = (const float*)d_in[5];
    const float* bq1 = (const float*)d_in[6];
    const float* wv1 = (const float*)d_in[7];
    const float* bv1 = (const float*)d_in[8];
    const float* ws1 = (const float*)d_in[9];
    const float* bs1 = (const float*)d_in[10];
    const float* g1  = (const float*)d_in[11];
    const float* be1 = (const float*)d_in[12];
    const float* wk2 = (const float*)d_in[13];
    const float* bk2 = (const float*)d_in[14];
    const float* wq2 = (const float*)d_in[15];
    const float* bq2 = (const float*)d_in[16];
    const float* wv2 = (const float*)d_in[17];
    const float* bv2 = (const float*)d_in[18];
    const float* ws2 = (const float*)d_in[19];
    const float* bs2 = (const float*)d_in[20];
    const float* g2  = (const float*)d_in[21];
    const float* be2 = (const float*)d_in[22];
    float* out = (float*)d_out;

    const size_t SZ_QV1 = (size_t)NNODES * 64 * 4;   // 32 MiB (uint[n][64])
    const size_t SZ_QV2 = (size_t)NNODES * 128 * 4;  // 64 MiB (uint[n][128])

    char* ws = (char*)d_ws;
    size_t off = 0;
    auto alloc = [&](size_t b) { size_t o = off; off += (b + 255) & ~(size_t)255; return o; };

    int* idx              = (int*)(ws + alloc((size_t)NNODES * NK * 4));
    size_t o_region       = alloc(2 * SZ_QV2);      // layer-2 qv/ks; layer-1 aliased in front
    unsigned int* qv1     = (unsigned int*)(ws + o_region);
    unsigned int* ks1     = (unsigned int*)(ws + o_region + SZ_QV1);
    unsigned int* qv2     = (unsigned int*)(ws + o_region);
    unsigned int* ks2     = (unsigned int*)(ws + o_region + SZ_QV2);
    unsigned short* h1    = (unsigned short*)(ws + alloc((size_t)NNODES * 64 * 2));
    unsigned short* h2    = (unsigned short*)(ws + alloc((size_t)NNODES * 128 * 2));
    unsigned short* frag  = (unsigned short*)(ws + alloc(64 * 64 * 8 * 2));
    float* part           = (float*)(ws + alloc((size_t)4096 * 2 * 128 * 4));
    float* ss1            = (float*)(ws + alloc(2 * 64 * 4));
    float* ss2            = (float*)(ws + alloc(2 * 128 * 4));
    (void)ws_size; (void)in_sizes; (void)n_in; (void)out_size;

    knn_kernel<<<BGR * 4, 256, 0, stream>>>(pos, idx);
    feat1_kernel<<<1024, 256, 0, stream>>>(x, wk1, bk1, wq1, bq1, wv1, bv1, ws1, bs1,
                                           qv1, ks1);
    conv_kernel<64><<<NNODES / 32, 256, 0, stream>>>(qv1, ks1, idx, h1, part);
    fin1_wfrag_kernel<<<128, 256, 0, stream>>>(part, g1, be1, ss1,
                                               wk2, wq2, wv2, ws2, frag);
    feat2_kernel<<<NNODES / 16, 256, 0, stream>>>(h1, frag, ss1, bk2, bq2, bv2, bs2,
                                                  qv2, ks2);
    conv_kernel<128><<<NNODES / 32, 256, 0, stream>>>(qv2, ks2, idx, h2, part);
    bnfin_kernel<128><<<128, 256, 0, stream>>>(part, g2, be2, ss2);
    pool_partial_kernel<<<BGR * 4, 256, 0, stream>>>(h2, ss2, part);
    pool_final_kernel<<<BGR, 128, 0, stream>>>(part, out);
}

// Round 9
// 259.741 us; speedup vs baseline: 2.1579x; 1.1153x over previous
//
#include <hip/hip_runtime.h>
#include <hip/hip_bf16.h>

#define BGR   128
#define NPER  1024
#define NK    7
#define NNODES (BGR*NPER)

typedef __attribute__((ext_vector_type(8))) short short8;
typedef __attribute__((ext_vector_type(8))) unsigned short ushort8;
typedef __attribute__((ext_vector_type(4))) float floatx4;

static __device__ __forceinline__ float bf2f(unsigned short u) {
    unsigned int x = ((unsigned int)u) << 16;
    return __builtin_bit_cast(float, x);
}
static __device__ __forceinline__ unsigned short f2bf(float f) {
    unsigned int x = __builtin_bit_cast(unsigned int, f);
    unsigned int lsb = (x >> 16) & 1u;
    x += 0x7fffu + lsb;
    return (unsigned short)(x >> 16);
}

// ---------------- 1: kNN — one-pass, dot-form distance, self-in-slot0, 8-slot med3 chain ----
// d' = |q|^2 - 2 p.q = |p-q|^2 - |p|^2 (same ordering; 3 fma). Self d' = -|p|^2 is the
// guaranteed minimum -> occupies b0 with no per-candidate self check; neighbors = b1..b7.
// packed = (bits(d') & ~1023) | j ; float bit-order == value order per sign class, and the
// med3 chain compares as floats, so the pack is order-preserving up to 13-bit quantization.
__global__ __launch_bounds__(256) void knn_kernel(const float* __restrict__ pos,
                                                  int* __restrict__ idx) {
    __shared__ __align__(16) floatx4 sp[NPER];
    int g = blockIdx.x >> 2;
    int i_local = ((blockIdx.x & 3) << 8) + threadIdx.x;
    int base = g * NPER;
    const float* pg = pos + (size_t)base * 3;
    for (int t = threadIdx.x; t < NPER * 3; t += 256) {
        float v = pg[t];
        int j = t / 3, comp = t - j * 3;
        ((float*)&sp[j])[comp] = v;
    }
    __syncthreads();
    for (int j = threadIdx.x; j < NPER; j += 256) {
        floatx4 q = sp[j];
        sp[j].w = fmaf(q.x, q.x, fmaf(q.y, q.y, q.z * q.z));
    }
    __syncthreads();
    floatx4 me = sp[i_local];
    float m2x = -2.f * me.x, m2y = -2.f * me.y, m2z = -2.f * me.z;

    float b0=3e38f,b1=3e38f,b2=3e38f,b3=3e38f,b4=3e38f,b5=3e38f,b6=3e38f,b7=3e38f;
    for (int j0 = 0; j0 < NPER; j0 += 8) {
        #pragma unroll
        for (int u = 0; u < 8; ++u) {
            floatx4 q = sp[j0 + u];
            float d = fmaf(m2x, q.x, fmaf(m2y, q.y, fmaf(m2z, q.z, q.w)));
            unsigned int ub = (__builtin_bit_cast(unsigned int, d) & 0xFFFFFC00u)
                              | (unsigned int)(j0 + u);
            float t = __builtin_bit_cast(float, ub);
            float n7 = __builtin_amdgcn_fmed3f(b6, b7, t);
            float n6 = __builtin_amdgcn_fmed3f(b5, b6, t);
            float n5 = __builtin_amdgcn_fmed3f(b4, b5, t);
            float n4 = __builtin_amdgcn_fmed3f(b3, b4, t);
            float n3 = __builtin_amdgcn_fmed3f(b2, b3, t);
            float n2 = __builtin_amdgcn_fmed3f(b1, b2, t);
            float n1 = __builtin_amdgcn_fmed3f(b0, b1, t);
            b0 = fminf(b0, t);
            b1 = n1; b2 = n2; b3 = n3; b4 = n4; b5 = n5; b6 = n6; b7 = n7;
        }
    }
    int* op = idx + (size_t)(base + i_local) * NK;
    op[0] = base + (int)(__builtin_bit_cast(unsigned int, b1) & 1023u);
    op[1] = base + (int)(__builtin_bit_cast(unsigned int, b2) & 1023u);
    op[2] = base + (int)(__builtin_bit_cast(unsigned int, b3) & 1023u);
    op[3] = base + (int)(__builtin_bit_cast(unsigned int, b4) & 1023u);
    op[4] = base + (int)(__builtin_bit_cast(unsigned int, b5) & 1023u);
    op[5] = base + (int)(__builtin_bit_cast(unsigned int, b6) & 1023u);
    op[6] = base + (int)(__builtin_bit_cast(unsigned int, b7) & 1023u);
}

// ---------------- 2: feat1 — x(16) -> packed qv1/ks1 uint[n][64] (lo=q/k, hi=v/s) ----------------
__global__ __launch_bounds__(256) void feat1_kernel(
    const float* __restrict__ x,
    const float* __restrict__ wk, const float* __restrict__ bk,
    const float* __restrict__ wq, const float* __restrict__ bq,
    const float* __restrict__ wv, const float* __restrict__ bv,
    const float* __restrict__ wsm, const float* __restrict__ bs,
    unsigned int* __restrict__ qv, unsigned int* __restrict__ ks) {
    int c = threadIdx.x & 63;
    float Wk[16], Wq[16], Wv[16], Ws[16];
    #pragma unroll
    for (int k = 0; k < 16; ++k) {
        Wk[k] = wk[k*64+c]; Wq[k] = wq[k*64+c]; Wv[k] = wv[k*64+c]; Ws[k] = wsm[k*64+c];
    }
    float Bk = bk[c], Bq = bq[c], Bv = bv[c], Bs = bs[c];
    int wave = blockIdx.x * (blockDim.x >> 6) + (threadIdx.x >> 6);
    int nw   = gridDim.x * (blockDim.x >> 6);
    for (int n = wave; n < NNODES; n += nw) {
        const float* xr = x + (size_t)n * 16;
        float ak = Bk, aq = Bq, av = Bv, as = Bs;
        #pragma unroll
        for (int k = 0; k < 16; ++k) {
            float xv = xr[k];
            ak += xv * Wk[k]; aq += xv * Wq[k]; av += xv * Wv[k]; as += xv * Ws[k];
        }
        size_t o = (size_t)n * 64 + c;
        qv[o] = ((unsigned int)f2bf(av) << 16) | f2bf(aq);
        ks[o] = ((unsigned int)f2bf(as) << 16) | f2bf(ak);
    }
}

// ---------------- 3: gated conv — scalar addressing + rcp sigmoid ----------------
template<int C>
__global__ __launch_bounds__(256) void conv_kernel(
    const unsigned int* __restrict__ qv, const unsigned int* __restrict__ ks,
    const int* __restrict__ idx, unsigned short* __restrict__ h,
    float* __restrict__ part) {
    const int NPB = 256 / C;
    int c   = threadIdx.x & (C - 1);
    int sub = __builtin_amdgcn_readfirstlane((int)(threadIdx.x / C));
    int b     = blockIdx.x;            // 4096 total = 128 graphs x 32
    int xcd   = b & 7;
    int chunk = b >> 3;
    int graph = xcd * 16 + (chunk >> 5);
    int nblk  = chunk & 31;
    int n0 = graph * NPER + nblk * 32;
    float s = 0.f, s2 = 0.f;
    #pragma unroll 2
    for (int i = sub; i < 32; i += NPB) {
        int n = n0 + i;                // wave-uniform (sub is SGPR)
        const int* nb = idx + (size_t)n * NK;
        unsigned int ku = ks[(size_t)n * C + c];
        float kv  = bf2f((unsigned short)(ku & 0xFFFF));
        float acc = bf2f((unsigned short)(ku >> 16));
        #pragma unroll
        for (int k = 0; k < NK; ++k) {
            int j = __builtin_amdgcn_readfirstlane(nb[k]);   // SGPR neighbor index
            const unsigned int* p = qv + (size_t)j * C;      // SGPR base
            unsigned int u = p[c];                           // s[base] + v_off load
            float qvv = bf2f((unsigned short)(u & 0xFFFF));
            float vvv = bf2f((unsigned short)(u >> 16));
            float t = kv + qvv;
            float sg = __builtin_amdgcn_rcpf(1.f + __expf(-t));
            acc = fmaf(sg, vvv, acc);
        }
        unsigned short hb = f2bf(acc);
        h[(size_t)n * C + c] = hb;
        float hv = bf2f(hb);
        s += hv; s2 += hv * hv;
    }
    __shared__ float ls[256], ls2[256];
    ls[threadIdx.x] = s; ls2[threadIdx.x] = s2;
    __syncthreads();
    if (threadIdx.x < C) {
        #pragma unroll
        for (int l = 1; l < NPB; ++l) { s += ls[threadIdx.x + l*C]; s2 += ls2[threadIdx.x + l*C]; }
        part[(size_t)blockIdx.x * 2 * C + threadIdx.x]     = s;
        part[(size_t)blockIdx.x * 2 * C + C + threadIdx.x] = s2;
    }
}

// ---------------- 4: BN finalize over 4096 block-partials (one block per channel) ----------------
template<int C>
static __device__ __forceinline__ void bnfin_body(
    const float* __restrict__ part, const float* __restrict__ gamma,
    const float* __restrict__ beta, float* __restrict__ ss,
    int c, float* ls, float* ls2) {
    float s = 0.f, s2 = 0.f;
    for (int b = threadIdx.x; b < 4096; b += 256) {
        s  += part[(size_t)b * 2 * C + c];
        s2 += part[(size_t)b * 2 * C + C + c];
    }
    ls[threadIdx.x] = s; ls2[threadIdx.x] = s2;
    __syncthreads();
    for (int st = 128; st > 0; st >>= 1) {
        if (threadIdx.x < st) { ls[threadIdx.x] += ls[threadIdx.x+st]; ls2[threadIdx.x] += ls2[threadIdx.x+st]; }
        __syncthreads();
    }
    if (threadIdx.x == 0) {
        float m   = ls[0] / (float)NNODES;
        float var = ls2[0] / (float)NNODES - m * m;
        float inv = rsqrtf(var + 1e-5f);
        float sc  = gamma[c] * inv;
        ss[c]     = sc;
        ss[C + c] = beta[c] - m * sc;
    }
}

template<int C>
__global__ __launch_bounds__(256) void bnfin_kernel(
    const float* __restrict__ part, const float* __restrict__ gamma,
    const float* __restrict__ beta, float* __restrict__ ss) {
    __shared__ float ls[256], ls2[256];
    bnfin_body<C>(part, gamma, beta, ss, blockIdx.x, ls, ls2);
}

// ---------------- 5: merged BN1-finalize (blocks 0..63) + wfrag (blocks 64..127) ----------------
__global__ __launch_bounds__(256) void fin1_wfrag_kernel(
    const float* __restrict__ part, const float* __restrict__ gamma,
    const float* __restrict__ beta, float* __restrict__ ss,
    const float* __restrict__ w0, const float* __restrict__ w1,
    const float* __restrict__ w2, const float* __restrict__ w3,
    unsigned short* __restrict__ frag) {
    __shared__ float ls[256], ls2[256];
    if (blockIdx.x < 64) {
        bnfin_body<64>(part, gamma, beta, ss, blockIdx.x, ls, ls2);
        return;
    }
    int s  = blockIdx.x - 64;
    if (threadIdx.x >= 64) return;
    int m  = s >> 4;
    int kt = (s >> 3) & 1;
    int ct = s & 7;
    const float* w = (m == 0) ? w0 : (m == 1) ? w1 : (m == 2) ? w2 : w3;
    int l = threadIdx.x;
    int col = ct * 16 + (l & 15);
    int kbase = kt * 32 + (l >> 4) * 8;
    unsigned short* out = frag + ((size_t)s * 64 + l) * 8;
    #pragma unroll
    for (int e = 0; e < 8; ++e) out[e] = f2bf(w[(size_t)(kbase + e) * 128 + col]);
}

// ---------------- 7: feat2 — BN1+ReLU fused load, MFMA, LDS-exchange dword stores -------------
// m=0:k, m=1:q (writers, pack lo) ; m=2:v, m=3:s (stage hi halves in LDS).
// qv2[n][128] uint = (v<<16)|q ; ks2[n][128] uint = (s<<16)|k — dense dword stores only.
__global__ __launch_bounds__(256) void feat2_kernel(
    const unsigned short* __restrict__ h1n, const unsigned short* __restrict__ frag,
    const float* __restrict__ ss1,
    const float* __restrict__ b0, const float* __restrict__ b1,
    const float* __restrict__ b2, const float* __restrict__ b3,
    unsigned int* __restrict__ qv2, unsigned int* __restrict__ ks2) {
    __shared__ unsigned short xh[2][2][16][17];   // [ct parity][v/s][row][col+pad]
    int nt = blockIdx.x;
    int m  = threadIdx.x >> 6;
    int l  = threadIdx.x & 63;
    const float* bm = (m == 0) ? b0 : (m == 1) ? b1 : (m == 2) ? b2 : b3;
    int lr = l & 15;
    int gq = l >> 4;
    int n  = nt * 16 + lr;
    const unsigned short* ar = h1n + (size_t)n * 64 + gq * 8;
    short8 a0r = *(const short8*)ar;
    short8 a1r = *(const short8*)(ar + 32);
    short8 a0, a1;
    #pragma unroll
    for (int e = 0; e < 8; ++e) {
        int c0 = gq * 8 + e;
        float f0 = bf2f((unsigned short)a0r[e]) * ss1[c0] + ss1[64 + c0];
        a0[e] = (short)f2bf(fmaxf(f0, 0.f));
        int c1 = 32 + gq * 8 + e;
        float f1 = bf2f((unsigned short)a1r[e]) * ss1[c1] + ss1[64 + c1];
        a1[e] = (short)f2bf(fmaxf(f1, 0.f));
    }
    #pragma unroll
    for (int ct = 0; ct < 8; ++ct) {
        size_t fb0 = ((size_t)(m * 16 + ct)     * 64 + l) * 8;
        size_t fb1 = ((size_t)(m * 16 + 8 + ct) * 64 + l) * 8;
        short8 w0 = *(const short8*)(frag + fb0);
        short8 w1 = *(const short8*)(frag + fb1);
        float bv = bm[ct * 16 + lr];
        floatx4 acc = {bv, bv, bv, bv};
        acc = __builtin_amdgcn_mfma_f32_16x16x32_bf16(a0, w0, acc, 0, 0, 0);
        acc = __builtin_amdgcn_mfma_f32_16x16x32_bf16(a1, w1, acc, 0, 0, 0);
        if (m >= 2) {
            #pragma unroll
            for (int r = 0; r < 4; ++r)
                xh[ct & 1][m - 2][gq * 4 + r][lr] = f2bf(acc[r]);
        }
        __syncthreads();
        if (m < 2) {
            unsigned int* od = (m == 1) ? qv2 : ks2;
            int set = (m == 1) ? 0 : 1;
            #pragma unroll
            for (int r = 0; r < 4; ++r) {
                unsigned int lo = f2bf(acc[r]);
                unsigned int hi = xh[ct & 1][set][gq * 4 + r][lr];
                od[(size_t)(nt * 16 + gq * 4 + r) * 128 + ct * 16 + lr] = (hi << 16) | lo;
            }
        }
    }
}

// ---------------- 8: mean-pool with fused BN2+ReLU, two-stage ----------------
__global__ __launch_bounds__(256) void pool_partial_kernel(const unsigned short* __restrict__ h2,
                                                           const float* __restrict__ ss2,
                                                           float* __restrict__ part) {
    int g = blockIdx.x >> 2;
    int q = blockIdx.x & 3;
    int c = threadIdx.x & 127;
    int isub = threadIdx.x >> 7;  // 0..1
    float sc = ss2[c], sh = ss2[128 + c];
    float acc = 0.f;
    const unsigned short* hp = h2 + ((size_t)g * NPER + q * 256) * 128;
    for (int i = isub; i < 256; i += 2)
        acc += fmaxf(bf2f(hp[(size_t)i * 128 + c]) * sc + sh, 0.f);
    __shared__ float red[256];
    red[threadIdx.x] = acc;
    __syncthreads();
    if (threadIdx.x < 128)
        part[(size_t)blockIdx.x * 128 + c] = acc + red[threadIdx.x + 128];
}

__global__ void pool_final_kernel(const float* __restrict__ part, float* __restrict__ out) {
    int g = blockIdx.x, c = threadIdx.x;
    float s = part[(size_t)(g*4+0)*128+c] + part[(size_t)(g*4+1)*128+c]
            + part[(size_t)(g*4+2)*128+c] + part[(size_t)(g*4+3)*128+c];
    out[(size_t)g * 128 + c] = s * (1.f / 1024.f);
}

extern "C" void kernel_launch(void* const* d_in, const int* in_sizes, int n_in,
                              void* d_out, int out_size, void* d_ws, size_t ws_size,
                              hipStream_t stream) {
    const float* x   = (const float*)d_in[0];
    const float* pos = (const float*)d_in[1];
    const float* wk1 = (const float*)d_in[3];
    const float* bk1 = (const float*)d_in[4];
    const float* wq1 = (const float*)d_in[5];
    const float* bq1 = (const float*)d_in[6];
    const float* wv1 = (const float*)d_in[7];
    const float* bv1 = (const float*)d_in[8];
    const float* ws1 = (const float*)d_in[9];
    const float* bs1 = (const float*)d_in[10];
    const float* g1  = (const float*)d_in[11];
    const float* be1 = (const float*)d_in[12];
    const float* wk2 = (const float*)d_in[13];
    const float* bk2 = (const float*)d_in[14];
    const float* wq2 = (const float*)d_in[15];
    const float* bq2 = (const float*)d_in[16];
    const float* wv2 = (const float*)d_in[17];
    const float* bv2 = (const float*)d_in[18];
    const float* ws2 = (const float*)d_in[19];
    const float* bs2 = (const float*)d_in[20];
    const float* g2  = (const float*)d_in[21];
    const float* be2 = (const float*)d_in[22];
    float* out = (float*)d_out;

    const size_t SZ_QV1 = (size_t)NNODES * 64 * 4;   // 32 MiB (uint[n][64])
    const size_t SZ_QV2 = (size_t)NNODES * 128 * 4;  // 64 MiB (uint[n][128])

    char* ws = (char*)d_ws;
    size_t off = 0;
    auto alloc = [&](size_t b) { size_t o = off; off += (b + 255) & ~(size_t)255; return o; };

    int* idx              = (int*)(ws + alloc((size_t)NNODES * NK * 4));
    size_t o_region       = alloc(2 * SZ_QV2);      // layer-2 qv/ks; layer-1 aliased in front
    unsigned int* qv1     = (unsigned int*)(ws + o_region);
    unsigned int* ks1     = (unsigned int*)(ws + o_region + SZ_QV1);
    unsigned int* qv2     = (unsigned int*)(ws + o_region);
    unsigned int* ks2     = (unsigned int*)(ws + o_region + SZ_QV2);
    unsigned short* h1    = (unsigned short*)(ws + alloc((size_t)NNODES * 64 * 2));
    unsigned short* h2    = (unsigned short*)(ws + alloc((size_t)NNODES * 128 * 2));
    unsigned short* frag  = (unsigned short*)(ws + alloc(64 * 64 * 8 * 2));
    float* part           = (float*)(ws + alloc((size_t)4096 * 2 * 128 * 4));
    float* ss1            = (float*)(ws + alloc(2 * 64 * 4));
    float* ss2            = (float*)(ws + alloc(2 * 128 * 4));
    (void)ws_size; (void)in_sizes; (void)n_in; (void)out_size;

    knn_kernel<<<BGR * 4, 256, 0, stream>>>(pos, idx);
    feat1_kernel<<<1024, 256, 0, stream>>>(x, wk1, bk1, wq1, bq1, wv1, bv1, ws1, bs1,
                                           qv1, ks1);
    conv_kernel<64><<<NNODES / 32, 256, 0, stream>>>(qv1, ks1, idx, h1, part);
    fin1_wfrag_kernel<<<128, 256, 0, stream>>>(part, g1, be1, ss1,
                                               wk2, wq2, wv2, ws2, frag);
    feat2_kernel<<<NNODES / 16, 256, 0, stream>>>(h1, frag, ss1, bk2, bq2, bv2, bs2,
                                                  qv2, ks2);
    conv_kernel<128><<<NNODES / 32, 256, 0, stream>>>(qv2, ks2, idx, h2, part);
    bnfin_kernel<128><<<128, 256, 0, stream>>>(part, g2, be2, ss2);
    pool_partial_kernel<<<BGR * 4, 256, 0, stream>>>(h2, ss2, part);
    pool_final_kernel<<<BGR, 128, 0, stream>>>(part, out);
}

// Round 10
// 257.346 us; speedup vs baseline: 2.1780x; 1.0093x over previous
//
#include <hip/hip_runtime.h>
#include <hip/hip_bf16.h>

#define BGR   128
#define NPER  1024
#define NK    7
#define NNODES (BGR*NPER)

typedef __attribute__((ext_vector_type(8))) short short8;
typedef __attribute__((ext_vector_type(8))) unsigned short ushort8;
typedef __attribute__((ext_vector_type(4))) float floatx4;

static __device__ __forceinline__ float bf2f(unsigned short u) {
    unsigned int x = ((unsigned int)u) << 16;
    return __builtin_bit_cast(float, x);
}
static __device__ __forceinline__ unsigned short f2bf(float f) {
    unsigned int x = __builtin_bit_cast(unsigned int, f);
    unsigned int lsb = (x >> 16) & 1u;
    x += 0x7fffu + lsb;
    return (unsigned short)(x >> 16);
}

// ---------------- 1: kNN — split-scan (2 threads/query) + bitonic truncated merge ----------
// Each thread scans one 512-candidate half with the 8-slot med3 chain (dot-form distance,
// packed index). Self d' = -|p|^2 is the global min and sits in exactly one half's slot 0.
// Merge: 7 smallest of union(A[1..7], B[0..7]) = { min(A[i+1], B[6-i]) } (both ascending).
__global__ __launch_bounds__(256) void knn_kernel(const float* __restrict__ pos,
                                                  int* __restrict__ idx) {
    __shared__ __align__(16) floatx4 sp[NPER];
    __shared__ float ex[256][9];            // padded: row stride 9 dwords kills bank conflicts
    int g     = blockIdx.x >> 3;
    int qbase = (blockIdx.x & 7) << 7;      // 128 queries per block
    int base  = g * NPER;
    const float* pg = pos + (size_t)base * 3;
    for (int t = threadIdx.x; t < NPER * 3; t += 256) {
        float v = pg[t];
        int j = t / 3, comp = t - j * 3;
        ((float*)&sp[j])[comp] = v;
    }
    __syncthreads();
    for (int j = threadIdx.x; j < NPER; j += 256) {
        floatx4 q = sp[j];
        sp[j].w = fmaf(q.x, q.x, fmaf(q.y, q.y, q.z * q.z));
    }
    __syncthreads();

    int qi = qbase + (threadIdx.x & 127);   // query (local node) this thread serves
    int hf = threadIdx.x >> 7;              // candidate half: 0 -> [0,512), 1 -> [512,1024)
    floatx4 me = sp[qi];
    float m2x = -2.f * me.x, m2y = -2.f * me.y, m2z = -2.f * me.z;

    float b0=3e38f,b1=3e38f,b2=3e38f,b3=3e38f,b4=3e38f,b5=3e38f,b6=3e38f,b7=3e38f;
    int j0base = hf << 9;
    for (int j0 = j0base; j0 < j0base + 512; j0 += 8) {
        #pragma unroll
        for (int u = 0; u < 8; ++u) {
            floatx4 q = sp[j0 + u];
            float d = fmaf(m2x, q.x, fmaf(m2y, q.y, fmaf(m2z, q.z, q.w)));
            unsigned int ub = (__builtin_bit_cast(unsigned int, d) & 0xFFFFFC00u)
                              | (unsigned int)(j0 + u);
            float t = __builtin_bit_cast(float, ub);
            float n7 = __builtin_amdgcn_fmed3f(b6, b7, t);
            float n6 = __builtin_amdgcn_fmed3f(b5, b6, t);
            float n5 = __builtin_amdgcn_fmed3f(b4, b5, t);
            float n4 = __builtin_amdgcn_fmed3f(b3, b4, t);
            float n3 = __builtin_amdgcn_fmed3f(b2, b3, t);
            float n2 = __builtin_amdgcn_fmed3f(b1, b2, t);
            float n1 = __builtin_amdgcn_fmed3f(b0, b1, t);
            b0 = fminf(b0, t);
            b1 = n1; b2 = n2; b3 = n3; b4 = n4; b5 = n5; b6 = n6; b7 = n7;
        }
    }
    float* er = ex[threadIdx.x];
    er[0]=b0; er[1]=b1; er[2]=b2; er[3]=b3; er[4]=b4; er[5]=b5; er[6]=b6; er[7]=b7;
    __syncthreads();
    if (threadIdx.x < 128) {
        int sh = qi >> 9;                   // which half contains self
        const float* A  = ex[threadIdx.x + (sh << 7)];        // self-half list (A[0]=self)
        const float* Bo = ex[threadIdx.x + ((1 - sh) << 7)];  // other-half list
        int* op = idx + (size_t)(base + qi) * NK;
        #pragma unroll
        for (int i = 0; i < 7; ++i) {
            float mm = fminf(A[i + 1], Bo[6 - i]);
            op[i] = base + (int)(__builtin_bit_cast(unsigned int, mm) & 1023u);
        }
    }
}

// ---------------- 2: feat1 — x(16) -> packed qv1/ks1 uint[n][64] (lo=q/k, hi=v/s) ----------------
__global__ __launch_bounds__(256) void feat1_kernel(
    const float* __restrict__ x,
    const float* __restrict__ wk, const float* __restrict__ bk,
    const float* __restrict__ wq, const float* __restrict__ bq,
    const float* __restrict__ wv, const float* __restrict__ bv,
    const float* __restrict__ wsm, const float* __restrict__ bs,
    unsigned int* __restrict__ qv, unsigned int* __restrict__ ks) {
    int c = threadIdx.x & 63;
    float Wk[16], Wq[16], Wv[16], Ws[16];
    #pragma unroll
    for (int k = 0; k < 16; ++k) {
        Wk[k] = wk[k*64+c]; Wq[k] = wq[k*64+c]; Wv[k] = wv[k*64+c]; Ws[k] = wsm[k*64+c];
    }
    float Bk = bk[c], Bq = bq[c], Bv = bv[c], Bs = bs[c];
    int wave = blockIdx.x * (blockDim.x >> 6) + (threadIdx.x >> 6);
    int nw   = gridDim.x * (blockDim.x >> 6);
    for (int n = wave; n < NNODES; n += nw) {
        const float* xr = x + (size_t)n * 16;
        float ak = Bk, aq = Bq, av = Bv, as = Bs;
        #pragma unroll
        for (int k = 0; k < 16; ++k) {
            float xv = xr[k];
            ak += xv * Wk[k]; aq += xv * Wq[k]; av += xv * Wv[k]; as += xv * Ws[k];
        }
        size_t o = (size_t)n * 64 + c;
        qv[o] = ((unsigned int)f2bf(av) << 16) | f2bf(aq);
        ks[o] = ((unsigned int)f2bf(as) << 16) | f2bf(ak);
    }
}

// ---------------- 3: gated conv — scalar addressing + rcp sigmoid ----------------
template<int C>
__global__ __launch_bounds__(256) void conv_kernel(
    const unsigned int* __restrict__ qv, const unsigned int* __restrict__ ks,
    const int* __restrict__ idx, unsigned short* __restrict__ h,
    float* __restrict__ part) {
    const int NPB = 256 / C;
    int c   = threadIdx.x & (C - 1);
    int sub = __builtin_amdgcn_readfirstlane((int)(threadIdx.x / C));
    int b     = blockIdx.x;            // 4096 total = 128 graphs x 32
    int xcd   = b & 7;
    int chunk = b >> 3;
    int graph = xcd * 16 + (chunk >> 5);
    int nblk  = chunk & 31;
    int n0 = graph * NPER + nblk * 32;
    float s = 0.f, s2 = 0.f;
    #pragma unroll 2
    for (int i = sub; i < 32; i += NPB) {
        int n = n0 + i;                // wave-uniform (sub is SGPR)
        const int* nb = idx + (size_t)n * NK;
        unsigned int ku = ks[(size_t)n * C + c];
        float kv  = bf2f((unsigned short)(ku & 0xFFFF));
        float acc = bf2f((unsigned short)(ku >> 16));
        #pragma unroll
        for (int k = 0; k < NK; ++k) {
            int j = __builtin_amdgcn_readfirstlane(nb[k]);   // SGPR neighbor index
            const unsigned int* p = qv + (size_t)j * C;      // SGPR base
            unsigned int u = p[c];                           // s[base] + v_off load
            float qvv = bf2f((unsigned short)(u & 0xFFFF));
            float vvv = bf2f((unsigned short)(u >> 16));
            float t = kv + qvv;
            float sg = __builtin_amdgcn_rcpf(1.f + __expf(-t));
            acc = fmaf(sg, vvv, acc);
        }
        unsigned short hb = f2bf(acc);
        h[(size_t)n * C + c] = hb;
        float hv = bf2f(hb);
        s += hv; s2 += hv * hv;
    }
    __shared__ float ls[256], ls2[256];
    ls[threadIdx.x] = s; ls2[threadIdx.x] = s2;
    __syncthreads();
    if (threadIdx.x < C) {
        #pragma unroll
        for (int l = 1; l < NPB; ++l) { s += ls[threadIdx.x + l*C]; s2 += ls2[threadIdx.x + l*C]; }
        part[(size_t)blockIdx.x * 2 * C + threadIdx.x]     = s;
        part[(size_t)blockIdx.x * 2 * C + C + threadIdx.x] = s2;
    }
}

// ---------------- 4: BN finalize over 4096 block-partials (one block per channel) ----------------
template<int C>
static __device__ __forceinline__ void bnfin_body(
    const float* __restrict__ part, const float* __restrict__ gamma,
    const float* __restrict__ beta, float* __restrict__ ss,
    int c, float* ls, float* ls2) {
    float s = 0.f, s2 = 0.f;
    for (int b = threadIdx.x; b < 4096; b += 256) {
        s  += part[(size_t)b * 2 * C + c];
        s2 += part[(size_t)b * 2 * C + C + c];
    }
    ls[threadIdx.x] = s; ls2[threadIdx.x] = s2;
    __syncthreads();
    for (int st = 128; st > 0; st >>= 1) {
        if (threadIdx.x < st) { ls[threadIdx.x] += ls[threadIdx.x+st]; ls2[threadIdx.x] += ls2[threadIdx.x+st]; }
        __syncthreads();
    }
    if (threadIdx.x == 0) {
        float m   = ls[0] / (float)NNODES;
        float var = ls2[0] / (float)NNODES - m * m;
        float inv = rsqrtf(var + 1e-5f);
        float sc  = gamma[c] * inv;
        ss[c]     = sc;
        ss[C + c] = beta[c] - m * sc;
    }
}

template<int C>
__global__ __launch_bounds__(256) void bnfin_kernel(
    const float* __restrict__ part, const float* __restrict__ gamma,
    const float* __restrict__ beta, float* __restrict__ ss) {
    __shared__ float ls[256], ls2[256];
    bnfin_body<C>(part, gamma, beta, ss, blockIdx.x, ls, ls2);
}

// ---------------- 5: merged BN1-finalize (blocks 0..63) + wfrag (blocks 64..127) ----------------
__global__ __launch_bounds__(256) void fin1_wfrag_kernel(
    const float* __restrict__ part, const float* __restrict__ gamma,
    const float* __restrict__ beta, float* __restrict__ ss,
    const float* __restrict__ w0, const float* __restrict__ w1,
    const float* __restrict__ w2, const float* __restrict__ w3,
    unsigned short* __restrict__ frag) {
    __shared__ float ls[256], ls2[256];
    if (blockIdx.x < 64) {
        bnfin_body<64>(part, gamma, beta, ss, blockIdx.x, ls, ls2);
        return;
    }
    int s  = blockIdx.x - 64;
    if (threadIdx.x >= 64) return;
    int m  = s >> 4;
    int kt = (s >> 3) & 1;
    int ct = s & 7;
    const float* w = (m == 0) ? w0 : (m == 1) ? w1 : (m == 2) ? w2 : w3;
    int l = threadIdx.x;
    int col = ct * 16 + (l & 15);
    int kbase = kt * 32 + (l >> 4) * 8;
    unsigned short* out = frag + ((size_t)s * 64 + l) * 8;
    #pragma unroll
    for (int e = 0; e < 8; ++e) out[e] = f2bf(w[(size_t)(kbase + e) * 128 + col]);
}

// ---------------- 7: feat2 — BN1+ReLU fused load, MFMA, LDS-exchange dword stores -------------
__global__ __launch_bounds__(256) void feat2_kernel(
    const unsigned short* __restrict__ h1n, const unsigned short* __restrict__ frag,
    const float* __restrict__ ss1,
    const float* __restrict__ b0, const float* __restrict__ b1,
    const float* __restrict__ b2, const float* __restrict__ b3,
    unsigned int* __restrict__ qv2, unsigned int* __restrict__ ks2) {
    __shared__ unsigned short xh[2][2][16][17];   // [ct parity][v/s][row][col+pad]
    int nt = blockIdx.x;
    int m  = threadIdx.x >> 6;
    int l  = threadIdx.x & 63;
    const float* bm = (m == 0) ? b0 : (m == 1) ? b1 : (m == 2) ? b2 : b3;
    int lr = l & 15;
    int gq = l >> 4;
    int n  = nt * 16 + lr;
    const unsigned short* ar = h1n + (size_t)n * 64 + gq * 8;
    short8 a0r = *(const short8*)ar;
    short8 a1r = *(const short8*)(ar + 32);
    short8 a0, a1;
    #pragma unroll
    for (int e = 0; e < 8; ++e) {
        int c0 = gq * 8 + e;
        float f0 = bf2f((unsigned short)a0r[e]) * ss1[c0] + ss1[64 + c0];
        a0[e] = (short)f2bf(fmaxf(f0, 0.f));
        int c1 = 32 + gq * 8 + e;
        float f1 = bf2f((unsigned short)a1r[e]) * ss1[c1] + ss1[64 + c1];
        a1[e] = (short)f2bf(fmaxf(f1, 0.f));
    }
    #pragma unroll
    for (int ct = 0; ct < 8; ++ct) {
        size_t fb0 = ((size_t)(m * 16 + ct)     * 64 + l) * 8;
        size_t fb1 = ((size_t)(m * 16 + 8 + ct) * 64 + l) * 8;
        short8 w0 = *(const short8*)(frag + fb0);
        short8 w1 = *(const short8*)(frag + fb1);
        float bv = bm[ct * 16 + lr];
        floatx4 acc = {bv, bv, bv, bv};
        acc = __builtin_amdgcn_mfma_f32_16x16x32_bf16(a0, w0, acc, 0, 0, 0);
        acc = __builtin_amdgcn_mfma_f32_16x16x32_bf16(a1, w1, acc, 0, 0, 0);
        if (m >= 2) {
            #pragma unroll
            for (int r = 0; r < 4; ++r)
                xh[ct & 1][m - 2][gq * 4 + r][lr] = f2bf(acc[r]);
        }
        __syncthreads();
        if (m < 2) {
            unsigned int* od = (m == 1) ? qv2 : ks2;
            int set = (m == 1) ? 0 : 1;
            #pragma unroll
            for (int r = 0; r < 4; ++r) {
                unsigned int lo = f2bf(acc[r]);
                unsigned int hi = xh[ct & 1][set][gq * 4 + r][lr];
                od[(size_t)(nt * 16 + gq * 4 + r) * 128 + ct * 16 + lr] = (hi << 16) | lo;
            }
        }
    }
}

// ---------------- 8: mean-pool with fused BN2+ReLU, two-stage ----------------
__global__ __launch_bounds__(256) void pool_partial_kernel(const unsigned short* __restrict__ h2,
                                                           const float* __restrict__ ss2,
                                                           float* __restrict__ part) {
    int g = blockIdx.x >> 2;
    int q = blockIdx.x & 3;
    int c = threadIdx.x & 127;
    int isub = threadIdx.x >> 7;  // 0..1
    float sc = ss2[c], sh = ss2[128 + c];
    float acc = 0.f;
    const unsigned short* hp = h2 + ((size_t)g * NPER + q * 256) * 128;
    for (int i = isub; i < 256; i += 2)
        acc += fmaxf(bf2f(hp[(size_t)i * 128 + c]) * sc + sh, 0.f);
    __shared__ float red[256];
    red[threadIdx.x] = acc;
    __syncthreads();
    if (threadIdx.x < 128)
        part[(size_t)blockIdx.x * 128 + c] = acc + red[threadIdx.x + 128];
}

__global__ void pool_final_kernel(const float* __restrict__ part, float* __restrict__ out) {
    int g = blockIdx.x, c = threadIdx.x;
    float s = part[(size_t)(g*4+0)*128+c] + part[(size_t)(g*4+1)*128+c]
            + part[(size_t)(g*4+2)*128+c] + part[(size_t)(g*4+3)*128+c];
    out[(size_t)g * 128 + c] = s * (1.f / 1024.f);
}

extern "C" void kernel_launch(void* const* d_in, const int* in_sizes, int n_in,
                              void* d_out, int out_size, void* d_ws, size_t ws_size,
                              hipStream_t stream) {
    const float* x   = (const float*)d_in[0];
    const float* pos = (const float*)d_in[1];
    const float* wk1 = (const float*)d_in[3];
    const float* bk1 = (const float*)d_in[4];
    const float* wq1 = (const float*)d_in[5];
    const float* bq1 = (const float*)d_in[6];
    const float* wv1 = (const float*)d_in[7];
    const float* bv1 = (const float*)d_in[8];
    const float* ws1 = (const float*)d_in[9];
    const float* bs1 = (const float*)d_in[10];
    const float* g1  = (const float*)d_in[11];
    const float* be1 = (const float*)d_in[12];
    const float* wk2 = (const float*)d_in[13];
    const float* bk2 = (const float*)d_in[14];
    const float* wq2 = (const float*)d_in[15];
    const float* bq2 = (const float*)d_in[16];
    const float* wv2 = (const float*)d_in[17];
    const float* bv2 = (const float*)d_in[18];
    const float* ws2 = (const float*)d_in[19];
    const float* bs2 = (const float*)d_in[20];
    const float* g2  = (const float*)d_in[21];
    const float* be2 = (const float*)d_in[22];
    float* out = (float*)d_out;

    const size_t SZ_QV1 = (size_t)NNODES * 64 * 4;   // 32 MiB (uint[n][64])
    const size_t SZ_QV2 = (size_t)NNODES * 128 * 4;  // 64 MiB (uint[n][128])

    char* ws = (char*)d_ws;
    size_t off = 0;
    auto alloc = [&](size_t b) { size_t o = off; off += (b + 255) & ~(size_t)255; return o; };

    int* idx              = (int*)(ws + alloc((size_t)NNODES * NK * 4));
    size_t o_region       = alloc(2 * SZ_QV2);      // layer-2 qv/ks; layer-1 aliased in front
    unsigned int* qv1     = (unsigned int*)(ws + o_region);
    unsigned int* ks1     = (unsigned int*)(ws + o_region + SZ_QV1);
    unsigned int* qv2     = (unsigned int*)(ws + o_region);
    unsigned int* ks2     = (unsigned int*)(ws + o_region + SZ_QV2);
    unsigned short* h1    = (unsigned short*)(ws + alloc((size_t)NNODES * 64 * 2));
    unsigned short* h2    = (unsigned short*)(ws + alloc((size_t)NNODES * 128 * 2));
    unsigned short* frag  = (unsigned short*)(ws + alloc(64 * 64 * 8 * 2));
    float* part           = (float*)(ws + alloc((size_t)4096 * 2 * 128 * 4));
    float* ss1            = (float*)(ws + alloc(2 * 64 * 4));
    float* ss2            = (float*)(ws + alloc(2 * 128 * 4));
    (void)ws_size; (void)in_sizes; (void)n_in; (void)out_size;

    knn_kernel<<<BGR * 8, 256, 0, stream>>>(pos, idx);
    feat1_kernel<<<1024, 256, 0, stream>>>(x, wk1, bk1, wq1, bq1, wv1, bv1, ws1, bs1,
                                           qv1, ks1);
    conv_kernel<64><<<NNODES / 32, 256, 0, stream>>>(qv1, ks1, idx, h1, part);
    fin1_wfrag_kernel<<<128, 256, 0, stream>>>(part, g1, be1, ss1,
                                               wk2, wq2, wv2, ws2, frag);
    feat2_kernel<<<NNODES / 16, 256, 0, stream>>>(h1, frag, ss1, bk2, bq2, bv2, bs2,
                                                  qv2, ks2);
    conv_kernel<128><<<NNODES / 32, 256, 0, stream>>>(qv2, ks2, idx, h2, part);
    bnfin_kernel<128><<<128, 256, 0, stream>>>(part, g2, be2, ss2);
    pool_partial_kernel<<<BGR * 4, 256, 0, stream>>>(h2, ss2, part);
    pool_final_kernel<<<BGR, 128, 0, stream>>>(part, out);
}